// Round 1
// baseline (1216.061 us; speedup 1.0000x reference)
//
#include <hip/hip_runtime.h>
#include <math.h>

// SequenceAttention on MI355X — Round 1: correct fp32 baseline.
// Pipeline: zero-out / index-compaction -> K,V,Q GEMMs -> per-(b,h) scores GEMM
// (written directly into unpacked_scores output) -> softmax stats -> feat GEMM
// (softmax weights recomputed on the fly) -> LN -> ag GEMM -> 3 residual blocks
// -> head GEMM (scattered) -> final LN(x + ag/sqrt2).
// ws footprint ~21.4 MB with buffer aliasing (sizes exact for N=4096,B=4,S=512).

constexpr int BK = 16;
enum { EPI_NONE = 0, EPI_BIAS_RELU = 1, EPI_BIAS = 2, EPI_RESID = 3 };

#define RSQRT2 0.70710678118654752f

__device__ __forceinline__ void micro_fma(float4 a, float4 b, float acc[4][4]) {
  float av[4] = {a.x, a.y, a.z, a.w};
  float bv[4] = {b.x, b.y, b.z, b.w};
#pragma unroll
  for (int i = 0; i < 4; ++i)
#pragma unroll
    for (int j = 0; j < 4; ++j) acc[i][j] = fmaf(av[i], bv[j], acc[i][j]);
}

// ---------------- generic tiled GEMM: C[M,N] = A[M,K] @ B[N,K]^T (+epilogue) --
template <int EPI>
__global__ __launch_bounds__(256) void gemm_k(
    const float* __restrict__ A, const float* __restrict__ B,
    float* __restrict__ C, int M, int N, int K, int lda, int ldb, int ldc,
    const float* __restrict__ bias, const float* __restrict__ Hin,
    const int* __restrict__ gatherA, const int* __restrict__ scatterC) {
  __shared__ float As[BK][64];
  __shared__ float Bs[BK][64];
  const int tid = threadIdx.x;
  const int m0 = blockIdx.y * 64, n0 = blockIdx.x * 64;
  const int tr = tid & 15, tc = tid >> 4;
  float acc[4][4] = {};
  for (int k0 = 0; k0 < K; k0 += BK) {
#pragma unroll
    for (int i = 0; i < 4; ++i) {  // A tile: 64 rows x 16 k (transposed stage)
      int idx = tid + i * 256;
      int r = idx >> 4, k = idx & 15;
      int gr = m0 + r;
      float v = 0.f;
      if (gr < M) {
        int ar = gatherA ? gatherA[gr] : gr;
        if (ar >= 0) v = A[(size_t)ar * lda + k0 + k];
      }
      As[k][r] = v;
    }
#pragma unroll
    for (int i = 0; i < 4; ++i) {  // B tile: 64 cols x 16 k
      int idx = tid + i * 256;
      int c = idx >> 4, k = idx & 15;
      int gc = n0 + c;
      Bs[k][c] = (gc < N) ? B[(size_t)gc * ldb + k0 + k] : 0.f;
    }
    __syncthreads();
#pragma unroll
    for (int k = 0; k < BK; ++k) {
      float4 a = *(const float4*)&As[k][tr * 4];
      float4 b = *(const float4*)&Bs[k][tc * 4];
      micro_fma(a, b, acc);
    }
    __syncthreads();
  }
#pragma unroll
  for (int i = 0; i < 4; ++i) {
    int r = m0 + tr * 4 + i;
    if (r >= M) continue;
    if (gatherA && gatherA[r] < 0) continue;
    int orow = scatterC ? scatterC[r] : r;
#pragma unroll
    for (int j = 0; j < 4; ++j) {
      int c = n0 + tc * 4 + j;
      if (c >= N) continue;
      float v = acc[i][j];
      if (EPI == EPI_BIAS_RELU) { v += bias[c]; v = fmaxf(v, 0.f); }
      else if (EPI == EPI_BIAS) { v += bias[c]; }
      else if (EPI == EPI_RESID) { v = (Hin[(size_t)r * ldc + c] + v + bias[c]) * RSQRT2; }
      C[(size_t)orow * ldc + c] = v;
    }
  }
}

// ---------------- scores: per (b,h): S_tile = Q_tile(64x64) @ K_bh(64x64)^T ---
__global__ __launch_bounds__(256) void scores_k(
    const float* __restrict__ Q, const float* __restrict__ Kb,
    const int* __restrict__ list, const int* __restrict__ orw,
    float* __restrict__ outs, int N) {
  int b = blockIdx.z >> 3, h = blockIdx.z & 7;
  int mt = blockIdx.y, st = blockIdx.x;
  const int* lst = list + (size_t)b * N + mt * 64;
  if (lst[0] < 0) return;  // packed list: empty tile
  const int* ors = orw + (size_t)b * N + mt * 64;
  __shared__ float Qs[BK][64];
  __shared__ float Ks[BK][64];
  int tid = threadIdx.x;
  int tr = tid & 15, tc = tid >> 4;
  float acc[4][4] = {};
  const float* Kbase = Kb + ((size_t)b * 512 + st * 64) * 512 + h * 64;
  for (int k0 = 0; k0 < 64; k0 += BK) {
#pragma unroll
    for (int i = 0; i < 4; ++i) {
      int idx = tid + i * 256;
      int r = idx >> 4, k = idx & 15;
      int m = lst[r];
      Qs[k][r] = (m >= 0) ? Q[(size_t)m * 512 + h * 64 + k0 + k] : 0.f;
    }
#pragma unroll
    for (int i = 0; i < 4; ++i) {
      int idx = tid + i * 256;
      int s = idx >> 4, k = idx & 15;
      Ks[k][s] = Kbase[(size_t)s * 512 + k0 + k];
    }
    __syncthreads();
#pragma unroll
    for (int k = 0; k < BK; ++k) {
      float4 a = *(const float4*)&Qs[k][tr * 4];
      float4 bv = *(const float4*)&Ks[k][tc * 4];
      micro_fma(a, bv, acc);
    }
    __syncthreads();
  }
#pragma unroll
  for (int i = 0; i < 4; ++i) {
    int lr = tr * 4 + i;
    int m = lst[lr];
    if (m < 0) continue;
    int orr = ors[lr];
#pragma unroll
    for (int j = 0; j < 4; ++j) {
      int s = st * 64 + tc * 4 + j;
      outs[(size_t)orr * 4096 + s * 8 + h] = acc[i][j] * 0.125f;  // /sqrt(64)
    }
  }
}

// ---------------- per-(m,h) softmax stats: max, 1/(sum(e*mask)+EPS*sum(e)) ----
__global__ __launch_bounds__(256) void stats_k(
    const float* __restrict__ outs, const int* __restrict__ pm,
    const int* __restrict__ batch, const float* __restrict__ mask,
    float* __restrict__ stats) {
  __shared__ float red[256];
  int m = blockIdx.x, tid = threadIdx.x;
  int orow = pm[m];
  int b = batch[orow];
  const float* row = outs + (size_t)orow * 4096;
  int h = tid & 7, sg = tid >> 3;  // 8 heads x 32 s-groups
  float vals[16];
#pragma unroll
  for (int i = 0; i < 16; ++i) vals[i] = row[(sg + i * 32) * 8 + h];
  float mx = -1e30f;
#pragma unroll
  for (int i = 0; i < 16; ++i) mx = fmaxf(mx, vals[i]);
  red[tid] = mx;
  __syncthreads();
  for (int off = 128; off >= 8; off >>= 1) {
    if (tid < off) red[tid] = fmaxf(red[tid], red[tid + off]);
    __syncthreads();
  }
  float hmax = red[h];
  __syncthreads();
  float se = 0.f, ms = 0.f;
  const float* mrow = mask + (size_t)b * 512;
#pragma unroll
  for (int i = 0; i < 16; ++i) {
    float e = expf(vals[i] - hmax);
    se += e;
    ms += e * mrow[sg + i * 32];
  }
  red[tid] = se;
  __syncthreads();
  for (int off = 128; off >= 8; off >>= 1) {
    if (tid < off) red[tid] += red[tid + off];
    __syncthreads();
  }
  float sumexp = red[h];
  __syncthreads();
  red[tid] = ms;
  __syncthreads();
  for (int off = 128; off >= 8; off >>= 1) {
    if (tid < off) red[tid] += red[tid + off];
    __syncthreads();
  }
  float msum = red[h];
  if (tid < 8) {
    float denom = msum + 1e-6f * sumexp;  // == sumexp*(msum/sumexp + EPS)
    stats[(size_t)m * 16 + tid * 2] = hmax;
    stats[(size_t)m * 16 + tid * 2 + 1] = 1.0f / denom;
  }
}

// ---------------- feat: per (b,h): feat_tile(64x64) = W(64xS) @ V_bh(Sx64) ----
__global__ __launch_bounds__(256) void feat_k(
    const float* __restrict__ outs, const float* __restrict__ V,
    const int* __restrict__ list, const int* __restrict__ orw,
    const float* __restrict__ stats, const float* __restrict__ mask,
    float* __restrict__ feat, int N) {
  int b = blockIdx.z >> 3, h = blockIdx.z & 7;
  int mt = blockIdx.y;
  const int* lst = list + (size_t)b * N + mt * 64;
  if (lst[0] < 0) return;
  const int* ors = orw + (size_t)b * N + mt * 64;
  __shared__ float Ws[BK][64];
  __shared__ float Vs[BK][64];
  __shared__ float mxs[64], invs[64];
  __shared__ int orl[64];
  int tid = threadIdx.x;
  if (tid < 64) {
    int m = lst[tid];
    orl[tid] = (m >= 0) ? ors[tid] : -1;
    mxs[tid] = (m >= 0) ? stats[(size_t)m * 16 + h * 2] : 0.f;
    invs[tid] = (m >= 0) ? stats[(size_t)m * 16 + h * 2 + 1] : 0.f;
  }
  __syncthreads();
  int tr = tid & 15, tc = tid >> 4;
  float acc[4][4] = {};
  const float* Vbase = V + (size_t)b * 512 * 512 + h * 64;
  const float* mrow = mask + (size_t)b * 512;
  for (int s0 = 0; s0 < 512; s0 += BK) {
#pragma unroll
    for (int i = 0; i < 4; ++i) {  // softmax weights recomputed on the fly
      int idx = tid + i * 256;
      int r = idx >> 4, k = idx & 15;
      int orr = orl[r];
      float wv = 0.f;
      if (orr >= 0) {
        float sc = outs[(size_t)orr * 4096 + (s0 + k) * 8 + h];
        wv = expf(sc - mxs[r]) * mrow[s0 + k] * invs[r];
      }
      Ws[k][r] = wv;
    }
#pragma unroll
    for (int i = 0; i < 4; ++i) {  // V chunk, coalesced rows
      int idx = tid + i * 256;
      int k = idx >> 6, d = idx & 63;
      Vs[k][d] = Vbase[(size_t)(s0 + k) * 512 + d];
    }
    __syncthreads();
#pragma unroll
    for (int k = 0; k < BK; ++k) {
      float4 a = *(const float4*)&Ws[k][tr * 4];
      float4 bv = *(const float4*)&Vs[k][tc * 4];
      micro_fma(a, bv, acc);
    }
    __syncthreads();
  }
#pragma unroll
  for (int i = 0; i < 4; ++i) {
    int lr = tr * 4 + i;
    int m = lst[lr];
    if (m < 0) continue;
#pragma unroll
    for (int j = 0; j < 4; ++j) {
      int d = tc * 4 + j;
      feat[(size_t)m * 512 + h * 64 + d] = acc[i][j];
    }
  }
}

// ---------------- LayerNorm over W (=256 or 512), eps=1e-5 -------------------
template <int W>
__global__ __launch_bounds__(256) void ln_k(const float* __restrict__ in,
                                            float* __restrict__ out,
                                            const float* __restrict__ g,
                                            const float* __restrict__ bb) {
  constexpr int PT = W / 256;
  __shared__ float red[256];
  int row = blockIdx.x, tid = threadIdx.x;
  const float* xr = in + (size_t)row * W;
  float v[PT];
  float s = 0.f, sq = 0.f;
#pragma unroll
  for (int p = 0; p < PT; ++p) {
    v[p] = xr[tid + p * 256];
    s += v[p];
    sq += v[p] * v[p];
  }
  red[tid] = s;
  __syncthreads();
  for (int off = 128; off; off >>= 1) {
    if (tid < off) red[tid] += red[tid + off];
    __syncthreads();
  }
  float mean = red[0] * (1.0f / W);
  __syncthreads();
  red[tid] = sq;
  __syncthreads();
  for (int off = 128; off; off >>= 1) {
    if (tid < off) red[tid] += red[tid + off];
    __syncthreads();
  }
  float var = red[0] * (1.0f / W) - mean * mean;
  float is = 1.0f / sqrtf(var + 1e-5f);
#pragma unroll
  for (int p = 0; p < PT; ++p) {
    int c = tid + p * 256;
    out[(size_t)row * W + c] = (v[p] - mean) * is * g[c] + bb[c];
  }
}

// ---------------- final: out_x = LN(x + scatter(ag)/sqrt2) -------------------
__global__ __launch_bounds__(256) void outx_k(
    const float* __restrict__ x, const float* __restrict__ ag,
    const int* __restrict__ inv, const float* __restrict__ g,
    const float* __restrict__ bb, float* __restrict__ out) {
  __shared__ float red[256];
  int n = blockIdx.x, tid = threadIdx.x;
  int mi = inv[n];
  float v = x[(size_t)n * 256 + tid];
  if (mi >= 0) v += ag[(size_t)mi * 256 + tid] * RSQRT2;
  red[tid] = v;
  __syncthreads();
  for (int off = 128; off; off >>= 1) {
    if (tid < off) red[tid] += red[tid + off];
    __syncthreads();
  }
  float mean = red[0] * (1.0f / 256.0f);
  __syncthreads();
  red[tid] = v * v;
  __syncthreads();
  for (int off = 128; off; off >>= 1) {
    if (tid < off) red[tid] += red[tid + off];
    __syncthreads();
  }
  float var = red[0] * (1.0f / 256.0f) - mean * mean;
  float is = 1.0f / sqrtf(var + 1e-5f);
  out[(size_t)n * 256 + tid] = (v - mean) * is * g[tid] + bb[tid];
}

// ---------------- small utility kernels --------------------------------------
__global__ void fill0_k(float* __restrict__ p, long n) {
  long i = ((long)blockIdx.x * blockDim.x + threadIdx.x) * 4;
  long stride = (long)gridDim.x * blockDim.x * 4;
  float4 z = {0.f, 0.f, 0.f, 0.f};
  for (; i + 3 < n; i += stride) *(float4*)(p + i) = z;
  if (blockIdx.x == 0 && threadIdx.x < (n & 3)) p[n - 1 - threadIdx.x] = 0.f;
}

__global__ void init_idx_k(int* __restrict__ list, int* __restrict__ orw,
                           int* __restrict__ inv, int* __restrict__ cnt, int N,
                           int B) {
  int i = blockIdx.x * 256 + threadIdx.x;
  if (i < B * N) {
    list[i] = -1;
    orw[i] = -1;
  }
  if (i < N) inv[i] = -1;
  if (i < B) cnt[i] = 0;
}

__global__ void compact_k(const int* __restrict__ pm,
                          const int* __restrict__ batch, int* __restrict__ list,
                          int* __restrict__ orw, int* __restrict__ inv,
                          int* __restrict__ cnt, int N) {
  int m = blockIdx.x * 256 + threadIdx.x;
  if (m >= N) return;
  int p = pm[m];
  int b = batch[p];
  int slot = atomicAdd(&cnt[b], 1);
  list[(size_t)b * N + slot] = m;
  orw[(size_t)b * N + slot] = p;
  inv[p] = m;
}

// -----------------------------------------------------------------------------
extern "C" void kernel_launch(void* const* d_in, const int* in_sizes, int n_in,
                              void* d_out, int out_size, void* d_ws,
                              size_t ws_size, hipStream_t stream) {
  const float* x = (const float*)d_in[0];
  const float* emb = (const float*)d_in[1];
  const float* mask = (const float*)d_in[2];
  const int* pm = (const int*)d_in[3];
  const int* batch = (const int*)d_in[4];
  const float* Wq = (const float*)d_in[5];
  const float* Wk = (const float*)d_in[6];
  const float* Wv = (const float*)d_in[7];
  const float* ag_s = (const float*)d_in[8];
  const float* ag_b = (const float*)d_in[9];
  const float* Wag = (const float*)d_in[10];
  const float* rls = (const float*)d_in[11];
  const float* rlb = (const float*)d_in[12];
  const float* rw1 = (const float*)d_in[13];
  const float* rb1 = (const float*)d_in[14];
  const float* rw2 = (const float*)d_in[15];
  const float* rb2 = (const float*)d_in[16];
  const float* hw = (const float*)d_in[17];
  const float* hb = (const float*)d_in[18];
  const float* ens = (const float*)d_in[19];
  const float* enb = (const float*)d_in[20];

  const int N = in_sizes[0] / 256;  // 4096
  const int B = in_sizes[2] / 512;  // 4

  // ws layout (floats), with aliasing after lifetimes end:
  float* w = (float*)d_ws;
  float* Kb = w;                                 // B*S*512   (later: h, lnfeat lo)
  float* Vb = Kb + (size_t)B * 512 * 512;        // B*S*512   (later: lnh, lnfeat hi)
  float* Qb = Vb + (size_t)B * 512 * 512;        // N*512     (later: feat, t)
  float* AGb = Qb + (size_t)N * 512;             // N*256     (live to the end)
  float* STb = AGb + (size_t)N * 256;            // N*8*2 stats
  int* ip = (int*)(STb + (size_t)N * 16);
  int* list = ip;
  int* orw = list + (size_t)B * N;
  int* inv = orw + (size_t)B * N;
  int* cnt = inv + N;
  float* FEATb = Qb;  // alias: Q dead after scores
  float* LNFb = Kb;   // alias: K+V dead after feat (needs N*512 == 2*B*S*512)
  float* Hb = Kb;     // alias: lnfeat dead after ag gemm
  float* LNHb = Vb;
  float* Tb = Qb;     // alias: feat dead after ln512

  float* out_x = (float*)d_out;
  float* out_lg = out_x + (size_t)N * 256;
  float* out_sc = out_lg + (size_t)N * 20;

  // 0. zero outputs (covers any rows not in prot_mask) + index init/compaction
  fill0_k<<<8192, 256, 0, stream>>>((float*)d_out, (long)out_size);
  init_idx_k<<<(B * N + 255) / 256, 256, 0, stream>>>(list, orw, inv, cnt, N, B);
  compact_k<<<(N + 255) / 256, 256, 0, stream>>>(pm, batch, list, orw, inv, cnt, N);

  // 1. K, V projections: (B*S,512) = emb(B*S,1280) @ W(512,1280)^T
  gemm_k<EPI_NONE><<<dim3(8, (B * 512) / 64), 256, 0, stream>>>(
      emb, Wk, Kb, B * 512, 512, 1280, 1280, 1280, 512, nullptr, nullptr, nullptr, nullptr);
  gemm_k<EPI_NONE><<<dim3(8, (B * 512) / 64), 256, 0, stream>>>(
      emb, Wv, Vb, B * 512, 512, 1280, 1280, 1280, 512, nullptr, nullptr, nullptr, nullptr);
  // 2. Q projection with row gather: Q[m] = x[pm[m]] @ Wq^T
  gemm_k<EPI_NONE><<<dim3(8, N / 64), 256, 0, stream>>>(
      x, Wq, Qb, N, 512, 256, 256, 256, 512, nullptr, nullptr, pm, nullptr);
  // 3. scores -> written directly to unpacked_scores output region
  scores_k<<<dim3(8, N / 64, B * 8), 256, 0, stream>>>(Qb, Kb, list, orw, out_sc, N);
  // 4. softmax stats per (m,h)
  stats_k<<<N, 256, 0, stream>>>(out_sc, pm, batch, mask, STb);
  // 5. feat = w @ V per (b,h)
  feat_k<<<dim3(1, N / 64, B * 8), 256, 0, stream>>>(out_sc, Vb, list, orw, STb, mask, FEATb, N);
  // 6. ag = LN(feat) @ Wag^T
  ln_k<512><<<N, 256, 0, stream>>>(FEATb, LNFb, ag_s, ag_b);
  gemm_k<EPI_NONE><<<dim3(4, N / 64), 256, 0, stream>>>(
      LNFb, Wag, AGb, N, 256, 512, 512, 512, 256, nullptr, nullptr, nullptr, nullptr);
  // 7. residual MLP blocks
  const float* hin = AGb;
  for (int i = 0; i < 3; ++i) {
    ln_k<256><<<N, 256, 0, stream>>>(hin, LNHb, rls + i * 256, rlb + i * 256);
    gemm_k<EPI_BIAS_RELU><<<dim3(4, N / 64), 256, 0, stream>>>(
        LNHb, rw1 + (size_t)i * 65536, Tb, N, 256, 256, 256, 256, 256,
        rb1 + i * 256, nullptr, nullptr, nullptr);
    gemm_k<EPI_RESID><<<dim3(4, N / 64), 256, 0, stream>>>(
        Tb, rw2 + (size_t)i * 65536, Hb, N, 256, 256, 256, 256, 256,
        rb2 + i * 256, hin, nullptr, nullptr);
    hin = Hb;
  }
  // 8. head logits, scattered to output rows pm[m]
  gemm_k<EPI_BIAS><<<dim3(1, N / 64), 256, 0, stream>>>(
      Hb, hw, out_lg, N, 20, 256, 256, 256, 20, hb, nullptr, nullptr, pm);
  // 9. out_x = LN(x + scatter(ag)/sqrt2)
  outx_k<<<N, 256, 0, stream>>>(x, AGb, inv, ens, enb, out_x);
}

// Round 2
// 643.207 us; speedup vs baseline: 1.8906x; 1.8906x over previous
//
#include <hip/hip_runtime.h>
#include <math.h>

// Round 2: all GEMM-shaped compute moved to bf16 MFMA (16x16x32), fp32 accum.
// 64x64 block tile, 4 waves each computing 32x32 via 4 MFMA per K-step of 32.
// LDS rows padded to 40 shorts (80B) -> conflict-free staging & frag reads.
// Q/K/V stored bf16; V transposed once so feat is a clean A*B^T GEMM.

typedef short bf8 __attribute__((ext_vector_type(8)));
typedef float f32x4 __attribute__((ext_vector_type(4)));
typedef unsigned short u16;

constexpr int LDT = 40;  // LDS row stride in shorts (32 data + 8 pad)
enum { EPI_NONE = 0, EPI_BIAS_RELU = 1, EPI_BIAS = 2, EPI_RESID = 3 };
#define RSQRT2 0.70710678118654752f

__device__ __forceinline__ u16 f2bf(float f) {
  unsigned int u = __builtin_bit_cast(unsigned int, f);
  unsigned int r = u + 0x7fffu + ((u >> 16) & 1u);  // RNE
  return (u16)(r >> 16);
}

__device__ __forceinline__ bf8 ldcvt8(const float* __restrict__ p) {
  f32x4 a = *(const f32x4*)p;
  f32x4 c = *(const f32x4*)(p + 4);
  bf8 v;
  v[0] = (short)f2bf(a[0]); v[1] = (short)f2bf(a[1]);
  v[2] = (short)f2bf(a[2]); v[3] = (short)f2bf(a[3]);
  v[4] = (short)f2bf(c[0]); v[5] = (short)f2bf(c[1]);
  v[6] = (short)f2bf(c[2]); v[7] = (short)f2bf(c[3]);
  return v;
}

__device__ __forceinline__ f32x4 mfma16(bf8 a, bf8 b, f32x4 c) {
  return __builtin_amdgcn_mfma_f32_16x16x32_bf16(a, b, c, 0, 0, 0);
}

// ---------------- generic MFMA GEMM: C[M,N] = A[M,K](f32) @ B[N,K](f32)^T ----
template <int EPI, bool BFOUT>
__global__ __launch_bounds__(256) void mgemm(
    const float* __restrict__ A, const float* __restrict__ B,
    void* __restrict__ Cv, int M, int N, int K, int lda, int ldb, int ldc,
    const float* __restrict__ bias, const float* __restrict__ Hin,
    const int* __restrict__ gatherA, const int* __restrict__ scatterC) {
  __shared__ __align__(16) u16 As[64 * LDT];
  __shared__ __align__(16) u16 Bs[64 * LDT];
  const int tid = threadIdx.x;
  const int m0 = blockIdx.y * 64, n0 = blockIdx.x * 64;
  const int wave = tid >> 6, lane = tid & 63;
  const int wm = (wave & 1) * 32, wn = (wave >> 1) * 32;
  const int lrow = lane & 15, quad = lane >> 4;
  const int srow = tid >> 2, skq = tid & 3;

  int agr = m0 + srow;
  int arow = (agr < M) ? (gatherA ? gatherA[agr] : agr) : -1;
  const float* Ap = (arow >= 0) ? A + (size_t)arow * lda + skq * 8 : nullptr;
  const float* Bp = (n0 + srow < N) ? B + (size_t)(n0 + srow) * ldb + skq * 8 : nullptr;
  u16* AsW = &As[srow * LDT + skq * 8];
  u16* BsW = &Bs[srow * LDT + skq * 8];
  const u16* Afr = &As[(wm + lrow) * LDT + quad * 8];
  const u16* Bfr = &Bs[(wn + lrow) * LDT + quad * 8];

  f32x4 acc00 = {0.f, 0.f, 0.f, 0.f}, acc01 = acc00, acc10 = acc00, acc11 = acc00;
  const bf8 z8 = {0, 0, 0, 0, 0, 0, 0, 0};

  for (int k0 = 0; k0 < K; k0 += 32) {
    bf8 av = Ap ? ldcvt8(Ap + k0) : z8;
    bf8 bv = Bp ? ldcvt8(Bp + k0) : z8;
    *(bf8*)AsW = av;
    *(bf8*)BsW = bv;
    __syncthreads();
    bf8 a0 = *(const bf8*)Afr;
    bf8 a1 = *(const bf8*)(Afr + 16 * LDT);
    bf8 b0 = *(const bf8*)Bfr;
    bf8 b1 = *(const bf8*)(Bfr + 16 * LDT);
    acc00 = mfma16(a0, b0, acc00);
    acc01 = mfma16(a0, b1, acc01);
    acc10 = mfma16(a1, b0, acc10);
    acc11 = mfma16(a1, b1, acc11);
    __syncthreads();
  }

  float* Cf = (float*)Cv;
  u16* Cb = (u16*)Cv;
#pragma unroll
  for (int mi = 0; mi < 2; ++mi) {
    f32x4 r0 = mi ? acc10 : acc00;
    f32x4 r1 = mi ? acc11 : acc01;
#pragma unroll
    for (int r = 0; r < 4; ++r) {
      int row = m0 + wm + mi * 16 + quad * 4 + r;
      if (row >= M) continue;
      if (gatherA && gatherA[row] < 0) continue;
      int orow = scatterC ? scatterC[row] : row;
#pragma unroll
      for (int ni = 0; ni < 2; ++ni) {
        int col = n0 + wn + ni * 16 + lrow;
        if (col >= N) continue;
        float v = ni ? r1[r] : r0[r];
        if (EPI == EPI_BIAS_RELU) v = fmaxf(v + bias[col], 0.f);
        else if (EPI == EPI_BIAS) v += bias[col];
        else if (EPI == EPI_RESID) v = (Hin[(size_t)row * ldc + col] + v + bias[col]) * RSQRT2;
        if (BFOUT) Cb[(size_t)orow * ldc + col] = f2bf(v);
        else Cf[(size_t)orow * ldc + col] = v;
      }
    }
  }
}

// ---------------- V transpose: V[b][s][hd] -> VT[b][hd][s] (bf16) ------------
__global__ __launch_bounds__(256) void vtrans(const u16* __restrict__ V,
                                              u16* __restrict__ VT) {
  __shared__ u16 t[32][33];
  int b = blockIdx.z;
  int s0 = blockIdx.x * 32, d0 = blockIdx.y * 32;
  int tx = threadIdx.x & 31, ty = threadIdx.x >> 5;
#pragma unroll
  for (int i = 0; i < 32; i += 8)
    t[ty + i][tx] = V[(size_t)(b * 512 + s0 + ty + i) * 512 + d0 + tx];
  __syncthreads();
#pragma unroll
  for (int i = 0; i < 32; i += 8)
    VT[(size_t)(b * 512 + d0 + ty + i) * 512 + s0 + tx] = t[tx][ty + i];
}

// ---------------- scores: per (b,h): 64m x 64s, K=64 -------------------------
__global__ __launch_bounds__(256) void scores_mfma(
    const u16* __restrict__ Q, const u16* __restrict__ Kb,
    const int* __restrict__ list, const int* __restrict__ orw,
    float* __restrict__ outs, int N) {
  int zb = blockIdx.z;
  int b = zb >> 3, h = zb & 7;
  int mt = blockIdx.y, st = blockIdx.x;
  const int* lst = list + (size_t)b * N + mt * 64;
  if (lst[0] < 0) return;
  const int* ors = orw + (size_t)b * N + mt * 64;
  __shared__ __align__(16) u16 Qs[64 * LDT];
  __shared__ __align__(16) u16 Ks[64 * LDT];
  __shared__ int mS[64], oS[64];
  int tid = threadIdx.x;
  if (tid < 64) { mS[tid] = lst[tid]; oS[tid] = ors[tid]; }
  int wave = tid >> 6, lane = tid & 63;
  int wm = (wave & 1) * 32, wn = (wave >> 1) * 32;
  int lrow = lane & 15, quad = lane >> 4;
  int srow = tid >> 2, skq = tid & 3;
  int m = lst[srow];
  const u16* Qp = (m >= 0) ? Q + (size_t)m * 512 + h * 64 + skq * 8 : nullptr;
  const u16* Kp = Kb + (size_t)(b * 512 + st * 64 + srow) * 512 + h * 64 + skq * 8;
  u16* QsW = &Qs[srow * LDT + skq * 8];
  u16* KsW = &Ks[srow * LDT + skq * 8];
  const u16* Afr = &Qs[(wm + lrow) * LDT + quad * 8];
  const u16* Bfr = &Ks[(wn + lrow) * LDT + quad * 8];
  f32x4 acc00 = {0.f, 0.f, 0.f, 0.f}, acc01 = acc00, acc10 = acc00, acc11 = acc00;
  const bf8 z8 = {0, 0, 0, 0, 0, 0, 0, 0};
#pragma unroll
  for (int k0 = 0; k0 < 64; k0 += 32) {
    bf8 qv = Qp ? *(const bf8*)(Qp + k0) : z8;
    bf8 kv = *(const bf8*)(Kp + k0);
    *(bf8*)QsW = qv;
    *(bf8*)KsW = kv;
    __syncthreads();
    bf8 a0 = *(const bf8*)Afr;
    bf8 a1 = *(const bf8*)(Afr + 16 * LDT);
    bf8 b0 = *(const bf8*)Bfr;
    bf8 b1 = *(const bf8*)(Bfr + 16 * LDT);
    acc00 = mfma16(a0, b0, acc00);
    acc01 = mfma16(a0, b1, acc01);
    acc10 = mfma16(a1, b0, acc10);
    acc11 = mfma16(a1, b1, acc11);
    __syncthreads();
  }
#pragma unroll
  for (int mi = 0; mi < 2; ++mi) {
    f32x4 r0 = mi ? acc10 : acc00;
    f32x4 r1 = mi ? acc11 : acc01;
#pragma unroll
    for (int r = 0; r < 4; ++r) {
      int lr = wm + mi * 16 + quad * 4 + r;
      int mm = mS[lr];
      if (mm < 0) continue;
      int orr = oS[lr];
#pragma unroll
      for (int ni = 0; ni < 2; ++ni) {
        int s = st * 64 + wn + ni * 16 + lrow;
        float v = (ni ? r1[r] : r0[r]) * 0.125f;
        outs[(size_t)orr * 4096 + s * 8 + h] = v;
      }
    }
  }
}

// ---------------- softmax stats per (m,h) ------------------------------------
__global__ __launch_bounds__(256) void stats_k(
    const float* __restrict__ outs, const int* __restrict__ pm,
    const int* __restrict__ batch, const float* __restrict__ mask,
    float* __restrict__ stats) {
  __shared__ float red[256];
  int m = blockIdx.x, tid = threadIdx.x;
  int orow = pm[m];
  int b = batch[orow];
  const float* row = outs + (size_t)orow * 4096;
  int h = tid & 7, sg = tid >> 3;
  float vals[16];
#pragma unroll
  for (int i = 0; i < 16; ++i) vals[i] = row[(sg + i * 32) * 8 + h];
  float mx = -1e30f;
#pragma unroll
  for (int i = 0; i < 16; ++i) mx = fmaxf(mx, vals[i]);
  red[tid] = mx;
  __syncthreads();
  for (int off = 128; off >= 8; off >>= 1) {
    if (tid < off) red[tid] = fmaxf(red[tid], red[tid + off]);
    __syncthreads();
  }
  float hmax = red[h];
  __syncthreads();
  float se = 0.f, ms = 0.f;
  const float* mrow = mask + (size_t)b * 512;
#pragma unroll
  for (int i = 0; i < 16; ++i) {
    float e = expf(vals[i] - hmax);
    se += e;
    ms += e * mrow[sg + i * 32];
  }
  red[tid] = se;
  __syncthreads();
  for (int off = 128; off >= 8; off >>= 1) {
    if (tid < off) red[tid] += red[tid + off];
    __syncthreads();
  }
  float sumexp = red[h];
  __syncthreads();
  red[tid] = ms;
  __syncthreads();
  for (int off = 128; off >= 8; off >>= 1) {
    if (tid < off) red[tid] += red[tid + off];
    __syncthreads();
  }
  float msum = red[h];
  if (tid < 8) {
    float denom = msum + 1e-6f * sumexp;
    stats[(size_t)m * 16 + tid * 2] = hmax;
    stats[(size_t)m * 16 + tid * 2 + 1] = 1.0f / denom;
  }
}

// ---------------- feat: per (b,h): 64m x 64d, K=S=512 ------------------------
__global__ __launch_bounds__(256) void feat_mfma(
    const float* __restrict__ outs, const u16* __restrict__ VT,
    const int* __restrict__ list, const int* __restrict__ orw,
    const float* __restrict__ stats, const float* __restrict__ mask,
    float* __restrict__ feat, int N) {
  int zb = blockIdx.z;
  int b = zb >> 3, h = zb & 7;
  int mt = blockIdx.y;
  const int* lst = list + (size_t)b * N + mt * 64;
  if (lst[0] < 0) return;
  const int* ors = orw + (size_t)b * N + mt * 64;
  __shared__ __align__(16) u16 Ws[64 * LDT];
  __shared__ __align__(16) u16 Vs[64 * LDT];
  __shared__ float mxs[64], ivs[64], mk[512];
  __shared__ int mS[64], oS[64];
  int tid = threadIdx.x;
  if (tid < 64) {
    int m = lst[tid];
    mS[tid] = m;
    oS[tid] = (m >= 0) ? ors[tid] : -1;
    mxs[tid] = (m >= 0) ? stats[(size_t)m * 16 + h * 2] : 0.f;
    ivs[tid] = (m >= 0) ? stats[(size_t)m * 16 + h * 2 + 1] : 0.f;
  }
  mk[tid] = mask[(size_t)b * 512 + tid];
  mk[tid + 256] = mask[(size_t)b * 512 + 256 + tid];
  __syncthreads();
  int wave = tid >> 6, lane = tid & 63;
  int wm = (wave & 1) * 32, wn = (wave >> 1) * 32;
  int lrow = lane & 15, quad = lane >> 4;
  int srow = tid >> 2, skq = tid & 3;
  int orr = oS[srow];
  float mx = mxs[srow], iv = ivs[srow];
  const float* scp = (orr >= 0) ? outs + (size_t)orr * 4096 + h : nullptr;
  const u16* Vp = VT + (size_t)(b * 512 + h * 64 + srow) * 512 + skq * 8;
  u16* WsW = &Ws[srow * LDT + skq * 8];
  u16* VsW = &Vs[srow * LDT + skq * 8];
  const u16* Afr = &Ws[(wm + lrow) * LDT + quad * 8];
  const u16* Bfr = &Vs[(wn + lrow) * LDT + quad * 8];
  f32x4 acc00 = {0.f, 0.f, 0.f, 0.f}, acc01 = acc00, acc10 = acc00, acc11 = acc00;
  for (int s0 = 0; s0 < 512; s0 += 32) {
    bf8 wv = {0, 0, 0, 0, 0, 0, 0, 0};
    if (scp) {
      int sb = s0 + skq * 8;
#pragma unroll
      for (int j = 0; j < 8; ++j) {
        float sc = scp[(size_t)(sb + j) * 8];
        float w = __expf(sc - mx) * mk[sb + j] * iv;
        wv[j] = (short)f2bf(w);
      }
    }
    bf8 vv = *(const bf8*)(Vp + s0);
    *(bf8*)WsW = wv;
    *(bf8*)VsW = vv;
    __syncthreads();
    bf8 a0 = *(const bf8*)Afr;
    bf8 a1 = *(const bf8*)(Afr + 16 * LDT);
    bf8 b0 = *(const bf8*)Bfr;
    bf8 b1 = *(const bf8*)(Bfr + 16 * LDT);
    acc00 = mfma16(a0, b0, acc00);
    acc01 = mfma16(a0, b1, acc01);
    acc10 = mfma16(a1, b0, acc10);
    acc11 = mfma16(a1, b1, acc11);
    __syncthreads();
  }
#pragma unroll
  for (int mi = 0; mi < 2; ++mi) {
    f32x4 r0 = mi ? acc10 : acc00;
    f32x4 r1 = mi ? acc11 : acc01;
#pragma unroll
    for (int r = 0; r < 4; ++r) {
      int lr = wm + mi * 16 + quad * 4 + r;
      int mm = mS[lr];
      if (mm < 0) continue;
#pragma unroll
      for (int ni = 0; ni < 2; ++ni) {
        int d = wn + ni * 16 + lrow;
        feat[(size_t)mm * 512 + h * 64 + d] = ni ? r1[r] : r0[r];
      }
    }
  }
}

// ---------------- LayerNorm over W, eps=1e-5 (in-place safe) -----------------
template <int W>
__global__ __launch_bounds__(256) void ln_k(const float* __restrict__ in,
                                            float* __restrict__ out,
                                            const float* __restrict__ g,
                                            const float* __restrict__ bb) {
  constexpr int PT = W / 256;
  __shared__ float red[256];
  int row = blockIdx.x, tid = threadIdx.x;
  const float* xr = in + (size_t)row * W;
  float v[PT];
  float s = 0.f, sq = 0.f;
#pragma unroll
  for (int p = 0; p < PT; ++p) {
    v[p] = xr[tid + p * 256];
    s += v[p];
    sq += v[p] * v[p];
  }
  red[tid] = s;
  __syncthreads();
  for (int off = 128; off; off >>= 1) {
    if (tid < off) red[tid] += red[tid + off];
    __syncthreads();
  }
  float mean = red[0] * (1.0f / W);
  __syncthreads();
  red[tid] = sq;
  __syncthreads();
  for (int off = 128; off; off >>= 1) {
    if (tid < off) red[tid] += red[tid + off];
    __syncthreads();
  }
  float var = red[0] * (1.0f / W) - mean * mean;
  float is = 1.0f / sqrtf(var + 1e-5f);
#pragma unroll
  for (int p = 0; p < PT; ++p) {
    int c = tid + p * 256;
    out[(size_t)row * W + c] = (v[p] - mean) * is * g[c] + bb[c];
  }
}

// ---------------- final: out_x = LN(x + scatter(ag)/sqrt2) -------------------
__global__ __launch_bounds__(256) void outx_k(
    const float* __restrict__ x, const float* __restrict__ ag,
    const int* __restrict__ inv, const float* __restrict__ g,
    const float* __restrict__ bb, float* __restrict__ out) {
  __shared__ float red[256];
  int n = blockIdx.x, tid = threadIdx.x;
  int mi = inv[n];
  float v = x[(size_t)n * 256 + tid];
  if (mi >= 0) v += ag[(size_t)mi * 256 + tid] * RSQRT2;
  red[tid] = v;
  __syncthreads();
  for (int off = 128; off; off >>= 1) {
    if (tid < off) red[tid] += red[tid + off];
    __syncthreads();
  }
  float mean = red[0] * (1.0f / 256.0f);
  __syncthreads();
  red[tid] = v * v;
  __syncthreads();
  for (int off = 128; off; off >>= 1) {
    if (tid < off) red[tid] += red[tid + off];
    __syncthreads();
  }
  float var = red[0] * (1.0f / 256.0f) - mean * mean;
  float is = 1.0f / sqrtf(var + 1e-5f);
  out[(size_t)n * 256 + tid] = (v - mean) * is * g[tid] + bb[tid];
}

// ---------------- index compaction -------------------------------------------
__global__ void init_idx_k(int* __restrict__ list, int* __restrict__ orw,
                           int* __restrict__ inv, int* __restrict__ cnt, int N,
                           int B) {
  int i = blockIdx.x * 256 + threadIdx.x;
  if (i < B * N) {
    list[i] = -1;
    orw[i] = -1;
  }
  if (i < N) inv[i] = -1;
  if (i < B) cnt[i] = 0;
}

__global__ void compact_k(const int* __restrict__ pm,
                          const int* __restrict__ batch, int* __restrict__ list,
                          int* __restrict__ orw, int* __restrict__ inv,
                          int* __restrict__ cnt, int N) {
  int m = blockIdx.x * 256 + threadIdx.x;
  if (m >= N) return;
  int p = pm[m];
  int b = batch[p];
  int slot = atomicAdd(&cnt[b], 1);
  list[(size_t)b * N + slot] = m;
  orw[(size_t)b * N + slot] = p;
  inv[p] = m;
}

// -----------------------------------------------------------------------------
extern "C" void kernel_launch(void* const* d_in, const int* in_sizes, int n_in,
                              void* d_out, int out_size, void* d_ws,
                              size_t ws_size, hipStream_t stream) {
  const float* x = (const float*)d_in[0];
  const float* emb = (const float*)d_in[1];
  const float* mask = (const float*)d_in[2];
  const int* pm = (const int*)d_in[3];
  const int* batch = (const int*)d_in[4];
  const float* Wq = (const float*)d_in[5];
  const float* Wk = (const float*)d_in[6];
  const float* Wv = (const float*)d_in[7];
  const float* ag_s = (const float*)d_in[8];
  const float* ag_b = (const float*)d_in[9];
  const float* Wag = (const float*)d_in[10];
  const float* rls = (const float*)d_in[11];
  const float* rlb = (const float*)d_in[12];
  const float* rw1 = (const float*)d_in[13];
  const float* rb1 = (const float*)d_in[14];
  const float* rw2 = (const float*)d_in[15];
  const float* rb2 = (const float*)d_in[16];
  const float* hw = (const float*)d_in[17];
  const float* hb = (const float*)d_in[18];
  const float* ens = (const float*)d_in[19];
  const float* enb = (const float*)d_in[20];

  const int N = in_sizes[0] / 256;  // 4096
  const int B = in_sizes[2] / 512;  // 4
  const size_t MB = 1024 * 1024;

  char* wsb = (char*)d_ws;
  // region 0..12MB: phase1 = Kbf(2MB)+Vbf(2MB)+Qbf(4MB); phase2 = featE(8MB);
  // phase3 = Hb(4MB)+LNb(4MB)+Tb(4MB)
  u16* Kbf = (u16*)wsb;
  u16* Vbf = (u16*)(wsb + 2 * MB);
  u16* Qbf = (u16*)(wsb + 4 * MB);
  float* featE = (float*)wsb;
  float* Hb = (float*)wsb;
  float* LNb = (float*)(wsb + 4 * MB);
  float* Tb = (float*)(wsb + 8 * MB);
  u16* VT = (u16*)(wsb + 12 * MB);     // 2MB, live scores..feat
  float* AG = (float*)(wsb + 14 * MB); // 4MB, live to end
  float* STb = (float*)(wsb + 18 * MB);
  int* list = (int*)(wsb + 18 * MB + 256 * 1024);
  int* orw = list + (size_t)B * N;
  int* inv = orw + (size_t)B * N;
  int* cnt = inv + N;

  float* out_x = (float*)d_out;
  float* out_lg = out_x + (size_t)N * 256;
  float* out_sc = out_lg + (size_t)N * 20;

  init_idx_k<<<(B * N + 255) / 256, 256, 0, stream>>>(list, orw, inv, cnt, N, B);
  compact_k<<<(N + 255) / 256, 256, 0, stream>>>(pm, batch, list, orw, inv, cnt, N);

  // projections -> bf16
  mgemm<EPI_NONE, true><<<dim3(8, (B * 512) / 64), 256, 0, stream>>>(
      emb, Wk, Kbf, B * 512, 512, 1280, 1280, 1280, 512, nullptr, nullptr, nullptr, nullptr);
  mgemm<EPI_NONE, true><<<dim3(8, (B * 512) / 64), 256, 0, stream>>>(
      emb, Wv, Vbf, B * 512, 512, 1280, 1280, 1280, 512, nullptr, nullptr, nullptr, nullptr);
  mgemm<EPI_NONE, true><<<dim3(8, N / 64), 256, 0, stream>>>(
      x, Wq, Qbf, N, 512, 256, 256, 256, 512, nullptr, nullptr, pm, nullptr);
  vtrans<<<dim3(16, 16, B), 256, 0, stream>>>(Vbf, VT);

  // attention
  scores_mfma<<<dim3(8, N / 64, B * 8), 256, 0, stream>>>(Qbf, Kbf, list, orw, out_sc, N);
  stats_k<<<N, 256, 0, stream>>>(out_sc, pm, batch, mask, STb);
  feat_mfma<<<dim3(1, N / 64, B * 8), 256, 0, stream>>>(out_sc, VT, list, orw, STb, mask, featE, N);

  // ag = LN(feat) @ Wag^T  (LN in-place)
  ln_k<512><<<N, 256, 0, stream>>>(featE, featE, ag_s, ag_b);
  mgemm<EPI_NONE, false><<<dim3(4, N / 64), 256, 0, stream>>>(
      featE, Wag, AG, N, 256, 512, 512, 512, 256, nullptr, nullptr, nullptr, nullptr);

  // residual MLP
  const float* hin = AG;
  for (int i = 0; i < 3; ++i) {
    ln_k<256><<<N, 256, 0, stream>>>(hin, LNb, rls + i * 256, rlb + i * 256);
    mgemm<EPI_BIAS_RELU, false><<<dim3(4, N / 64), 256, 0, stream>>>(
        LNb, rw1 + (size_t)i * 65536, Tb, N, 256, 256, 256, 256, 256,
        rb1 + i * 256, nullptr, nullptr, nullptr);
    mgemm<EPI_RESID, false><<<dim3(4, N / 64), 256, 0, stream>>>(
        Tb, rw2 + (size_t)i * 65536, Hb, N, 256, 256, 256, 256, 256,
        rb2 + i * 256, hin, nullptr, nullptr);
    hin = Hb;
  }
  // head (scatter rows to pm)
  mgemm<EPI_BIAS, false><<<dim3(1, N / 64), 256, 0, stream>>>(
      Hb, hw, out_lg, N, 20, 256, 256, 256, 20, hb, nullptr, nullptr, pm);
  // final LN
  outx_k<<<N, 256, 0, stream>>>(x, AG, inv, ens, enb, out_x);
}

// Round 3
// 475.034 us; speedup vs baseline: 2.5599x; 1.3540x over previous
//
#include <hip/hip_runtime.h>
#include <math.h>

// Round 3: packed bf16 score buffer [h][m][s] kills feat's scattered loads.
// scores -> packed (coalesced) ; unpack_k emits the strided fp32 output;
// stats/feat read packed with contiguous bf8 loads.

typedef short bf8 __attribute__((ext_vector_type(8)));
typedef float f32x4 __attribute__((ext_vector_type(4)));
typedef unsigned short u16;

constexpr int LDT = 40;  // LDS row stride in shorts (32 data + 8 pad)
enum { EPI_NONE = 0, EPI_BIAS_RELU = 1, EPI_BIAS = 2, EPI_RESID = 3 };
#define RSQRT2 0.70710678118654752f

__device__ __forceinline__ u16 f2bf(float f) {
  unsigned int u = __builtin_bit_cast(unsigned int, f);
  unsigned int r = u + 0x7fffu + ((u >> 16) & 1u);  // RNE
  return (u16)(r >> 16);
}
__device__ __forceinline__ float bf2f(u16 v) {
  return __builtin_bit_cast(float, (unsigned int)v << 16);
}

__device__ __forceinline__ bf8 ldcvt8(const float* __restrict__ p) {
  f32x4 a = *(const f32x4*)p;
  f32x4 c = *(const f32x4*)(p + 4);
  bf8 v;
  v[0] = (short)f2bf(a[0]); v[1] = (short)f2bf(a[1]);
  v[2] = (short)f2bf(a[2]); v[3] = (short)f2bf(a[3]);
  v[4] = (short)f2bf(c[0]); v[5] = (short)f2bf(c[1]);
  v[6] = (short)f2bf(c[2]); v[7] = (short)f2bf(c[3]);
  return v;
}

__device__ __forceinline__ f32x4 mfma16(bf8 a, bf8 b, f32x4 c) {
  return __builtin_amdgcn_mfma_f32_16x16x32_bf16(a, b, c, 0, 0, 0);
}

// ---------------- generic MFMA GEMM: C[M,N] = A[M,K](f32) @ B[N,K](f32)^T ----
template <int EPI, bool BFOUT>
__global__ __launch_bounds__(256) void mgemm(
    const float* __restrict__ A, const float* __restrict__ B,
    void* __restrict__ Cv, int M, int N, int K, int lda, int ldb, int ldc,
    const float* __restrict__ bias, const float* __restrict__ Hin,
    const int* __restrict__ gatherA, const int* __restrict__ scatterC) {
  __shared__ __align__(16) u16 As[64 * LDT];
  __shared__ __align__(16) u16 Bs[64 * LDT];
  const int tid = threadIdx.x;
  const int m0 = blockIdx.y * 64, n0 = blockIdx.x * 64;
  const int wave = tid >> 6, lane = tid & 63;
  const int wm = (wave & 1) * 32, wn = (wave >> 1) * 32;
  const int lrow = lane & 15, quad = lane >> 4;
  const int srow = tid >> 2, skq = tid & 3;

  int agr = m0 + srow;
  int arow = (agr < M) ? (gatherA ? gatherA[agr] : agr) : -1;
  const float* Ap = (arow >= 0) ? A + (size_t)arow * lda + skq * 8 : nullptr;
  const float* Bp = (n0 + srow < N) ? B + (size_t)(n0 + srow) * ldb + skq * 8 : nullptr;
  u16* AsW = &As[srow * LDT + skq * 8];
  u16* BsW = &Bs[srow * LDT + skq * 8];
  const u16* Afr = &As[(wm + lrow) * LDT + quad * 8];
  const u16* Bfr = &Bs[(wn + lrow) * LDT + quad * 8];

  f32x4 acc00 = {0.f, 0.f, 0.f, 0.f}, acc01 = acc00, acc10 = acc00, acc11 = acc00;
  const bf8 z8 = {0, 0, 0, 0, 0, 0, 0, 0};

  for (int k0 = 0; k0 < K; k0 += 32) {
    bf8 av = Ap ? ldcvt8(Ap + k0) : z8;
    bf8 bv = Bp ? ldcvt8(Bp + k0) : z8;
    *(bf8*)AsW = av;
    *(bf8*)BsW = bv;
    __syncthreads();
    bf8 a0 = *(const bf8*)Afr;
    bf8 a1 = *(const bf8*)(Afr + 16 * LDT);
    bf8 b0 = *(const bf8*)Bfr;
    bf8 b1 = *(const bf8*)(Bfr + 16 * LDT);
    acc00 = mfma16(a0, b0, acc00);
    acc01 = mfma16(a0, b1, acc01);
    acc10 = mfma16(a1, b0, acc10);
    acc11 = mfma16(a1, b1, acc11);
    __syncthreads();
  }

  float* Cf = (float*)Cv;
  u16* Cb = (u16*)Cv;
#pragma unroll
  for (int mi = 0; mi < 2; ++mi) {
    f32x4 r0 = mi ? acc10 : acc00;
    f32x4 r1 = mi ? acc11 : acc01;
#pragma unroll
    for (int r = 0; r < 4; ++r) {
      int row = m0 + wm + mi * 16 + quad * 4 + r;
      if (row >= M) continue;
      if (gatherA && gatherA[row] < 0) continue;
      int orow = scatterC ? scatterC[row] : row;
#pragma unroll
      for (int ni = 0; ni < 2; ++ni) {
        int col = n0 + wn + ni * 16 + lrow;
        if (col >= N) continue;
        float v = ni ? r1[r] : r0[r];
        if (EPI == EPI_BIAS_RELU) v = fmaxf(v + bias[col], 0.f);
        else if (EPI == EPI_BIAS) v += bias[col];
        else if (EPI == EPI_RESID) v = (Hin[(size_t)row * ldc + col] + v + bias[col]) * RSQRT2;
        if (BFOUT) Cb[(size_t)orow * ldc + col] = f2bf(v);
        else Cf[(size_t)orow * ldc + col] = v;
      }
    }
  }
}

// ---------------- V transpose: V[b][s][hd] -> VT[b][hd][s] (bf16) ------------
__global__ __launch_bounds__(256) void vtrans(const u16* __restrict__ V,
                                              u16* __restrict__ VT) {
  __shared__ u16 t[32][33];
  int b = blockIdx.z;
  int s0 = blockIdx.x * 32, d0 = blockIdx.y * 32;
  int tx = threadIdx.x & 31, ty = threadIdx.x >> 5;
#pragma unroll
  for (int i = 0; i < 32; i += 8)
    t[ty + i][tx] = V[(size_t)(b * 512 + s0 + ty + i) * 512 + d0 + tx];
  __syncthreads();
#pragma unroll
  for (int i = 0; i < 32; i += 8)
    VT[(size_t)(b * 512 + d0 + ty + i) * 512 + s0 + tx] = t[tx][ty + i];
}

// ---------------- scores: per (b,h): 64m x 64s -> packed[h][m][s] bf16 -------
__global__ __launch_bounds__(256) void scores_mfma(
    const u16* __restrict__ Q, const u16* __restrict__ Kb,
    const int* __restrict__ list, u16* __restrict__ packed, int N) {
  int zb = blockIdx.z;
  int b = zb >> 3, h = zb & 7;
  int mt = blockIdx.y, st = blockIdx.x;
  const int* lst = list + (size_t)b * N + mt * 64;
  if (lst[0] < 0) return;
  __shared__ __align__(16) u16 Qs[64 * LDT];
  __shared__ __align__(16) u16 Ks[64 * LDT];
  __shared__ int mS[64];
  int tid = threadIdx.x;
  if (tid < 64) mS[tid] = lst[tid];
  int wave = tid >> 6, lane = tid & 63;
  int wm = (wave & 1) * 32, wn = (wave >> 1) * 32;
  int lrow = lane & 15, quad = lane >> 4;
  int srow = tid >> 2, skq = tid & 3;
  int m = lst[srow];
  const u16* Qp = (m >= 0) ? Q + (size_t)m * 512 + h * 64 + skq * 8 : nullptr;
  const u16* Kp = Kb + (size_t)(b * 512 + st * 64 + srow) * 512 + h * 64 + skq * 8;
  u16* QsW = &Qs[srow * LDT + skq * 8];
  u16* KsW = &Ks[srow * LDT + skq * 8];
  const u16* Afr = &Qs[(wm + lrow) * LDT + quad * 8];
  const u16* Bfr = &Ks[(wn + lrow) * LDT + quad * 8];
  f32x4 acc00 = {0.f, 0.f, 0.f, 0.f}, acc01 = acc00, acc10 = acc00, acc11 = acc00;
  const bf8 z8 = {0, 0, 0, 0, 0, 0, 0, 0};
#pragma unroll
  for (int k0 = 0; k0 < 64; k0 += 32) {
    bf8 qv = Qp ? *(const bf8*)(Qp + k0) : z8;
    bf8 kv = *(const bf8*)(Kp + k0);
    *(bf8*)QsW = qv;
    *(bf8*)KsW = kv;
    __syncthreads();
    bf8 a0 = *(const bf8*)Afr;
    bf8 a1 = *(const bf8*)(Afr + 16 * LDT);
    bf8 b0 = *(const bf8*)Bfr;
    bf8 b1 = *(const bf8*)(Bfr + 16 * LDT);
    acc00 = mfma16(a0, b0, acc00);
    acc01 = mfma16(a0, b1, acc01);
    acc10 = mfma16(a1, b0, acc10);
    acc11 = mfma16(a1, b1, acc11);
    __syncthreads();
  }
#pragma unroll
  for (int mi = 0; mi < 2; ++mi) {
    f32x4 r0 = mi ? acc10 : acc00;
    f32x4 r1 = mi ? acc11 : acc01;
#pragma unroll
    for (int r = 0; r < 4; ++r) {
      int lr = wm + mi * 16 + quad * 4 + r;
      int mm = mS[lr];
      if (mm < 0) continue;
      u16* prow = packed + ((size_t)h * N + mm) * 512 + st * 64;
#pragma unroll
      for (int ni = 0; ni < 2; ++ni)
        prow[wn + ni * 16 + lrow] = f2bf((ni ? r1[r] : r0[r]) * 0.125f);
    }
  }
}

// ---------------- unpack: packed[h][m][s] -> out_sc[pm[m]][s][h] fp32 --------
__global__ __launch_bounds__(256) void unpack_k(const u16* __restrict__ packed,
                                                const int* __restrict__ pm,
                                                float* __restrict__ out_sc,
                                                int N) {
  __shared__ u16 Ls[8 * 520];
  int m = blockIdx.x, tid = threadIdx.x;
  int h = tid >> 5, c = (tid & 31) * 16;
  const u16* row = packed + ((size_t)h * N + m) * 512 + c;
  *(bf8*)&Ls[h * 520 + c] = *(const bf8*)row;
  *(bf8*)&Ls[h * 520 + c + 8] = *(const bf8*)(row + 8);
  __syncthreads();
  float* orow = out_sc + (size_t)pm[m] * 4096;
#pragma unroll
  for (int i = 0; i < 16; ++i) {
    int e = tid + i * 256;
    orow[e] = bf2f(Ls[(e & 7) * 520 + (e >> 3)]);
  }
}

// ---------------- softmax stats per (m,h) from packed ------------------------
__global__ __launch_bounds__(256) void stats_k(
    const u16* __restrict__ packed, const int* __restrict__ pm,
    const int* __restrict__ batch, const float* __restrict__ mask,
    float* __restrict__ stats, int N) {
  __shared__ float red[256];
  int m = blockIdx.x, tid = threadIdx.x;
  int h = tid >> 5, t = tid & 31;
  int b = batch[pm[m]];
  const u16* row = packed + ((size_t)h * N + m) * 512;
  float vals[16];
#pragma unroll
  for (int i = 0; i < 16; ++i) vals[i] = bf2f(row[t + i * 32]);
  float mx = -1e30f;
#pragma unroll
  for (int i = 0; i < 16; ++i) mx = fmaxf(mx, vals[i]);
  red[tid] = mx;
  __syncthreads();
  for (int off = 16; off; off >>= 1) {
    if (t < off) red[tid] = fmaxf(red[tid], red[tid + off]);
    __syncthreads();
  }
  float hmax = red[tid & ~31];
  __syncthreads();
  const float* mrow = mask + (size_t)b * 512;
  float se = 0.f, ms = 0.f;
#pragma unroll
  for (int i = 0; i < 16; ++i) {
    float e = __expf(vals[i] - hmax);
    se += e;
    ms += e * mrow[t + i * 32];
  }
  red[tid] = se;
  __syncthreads();
  for (int off = 16; off; off >>= 1) {
    if (t < off) red[tid] += red[tid + off];
    __syncthreads();
  }
  float sumexp = red[tid & ~31];
  __syncthreads();
  red[tid] = ms;
  __syncthreads();
  for (int off = 16; off; off >>= 1) {
    if (t < off) red[tid] += red[tid + off];
    __syncthreads();
  }
  float msum = red[tid & ~31];
  if (t == 0) {
    stats[(size_t)m * 16 + h * 2] = hmax;
    stats[(size_t)m * 16 + h * 2 + 1] = 1.0f / (msum + 1e-6f * sumexp);
  }
}

// ---------------- feat: per (b,h): 64m x 64d, K=S=512, W from packed ---------
__global__ __launch_bounds__(256) void feat_mfma(
    const u16* __restrict__ packed, const u16* __restrict__ VT,
    const int* __restrict__ list, const float* __restrict__ stats,
    const float* __restrict__ mask, float* __restrict__ feat, int N) {
  int zb = blockIdx.z;
  int b = zb >> 3, h = zb & 7;
  int mt = blockIdx.y;
  const int* lst = list + (size_t)b * N + mt * 64;
  if (lst[0] < 0) return;
  __shared__ __align__(16) u16 Ws[64 * LDT];
  __shared__ __align__(16) u16 Vs[64 * LDT];
  __shared__ float mxs[64], ivs[64], mk[512];
  __shared__ int mS[64];
  int tid = threadIdx.x;
  if (tid < 64) {
    int m = lst[tid];
    mS[tid] = m;
    mxs[tid] = (m >= 0) ? stats[(size_t)m * 16 + h * 2] : 0.f;
    ivs[tid] = (m >= 0) ? stats[(size_t)m * 16 + h * 2 + 1] : 0.f;
  }
  mk[tid] = mask[(size_t)b * 512 + tid];
  mk[tid + 256] = mask[(size_t)b * 512 + 256 + tid];
  __syncthreads();
  int wave = tid >> 6, lane = tid & 63;
  int wm = (wave & 1) * 32, wn = (wave >> 1) * 32;
  int lrow = lane & 15, quad = lane >> 4;
  int srow = tid >> 2, skq = tid & 3;
  int m = mS[srow];
  float mx = mxs[srow], iv = ivs[srow];
  const u16* scp = (m >= 0) ? packed + ((size_t)h * N + m) * 512 : nullptr;
  const u16* Vp = VT + (size_t)(b * 512 + h * 64 + srow) * 512 + skq * 8;
  u16* WsW = &Ws[srow * LDT + skq * 8];
  u16* VsW = &Vs[srow * LDT + skq * 8];
  const u16* Afr = &Ws[(wm + lrow) * LDT + quad * 8];
  const u16* Bfr = &Vs[(wn + lrow) * LDT + quad * 8];
  f32x4 acc00 = {0.f, 0.f, 0.f, 0.f}, acc01 = acc00, acc10 = acc00, acc11 = acc00;
  for (int s0 = 0; s0 < 512; s0 += 32) {
    bf8 wv = {0, 0, 0, 0, 0, 0, 0, 0};
    if (scp) {
      int sb = s0 + skq * 8;
      bf8 raw = *(const bf8*)(scp + sb);
#pragma unroll
      for (int j = 0; j < 8; ++j) {
        float w = __expf(bf2f((u16)raw[j]) - mx) * mk[sb + j] * iv;
        wv[j] = (short)f2bf(w);
      }
    }
    bf8 vv = *(const bf8*)(Vp + s0);
    *(bf8*)WsW = wv;
    *(bf8*)VsW = vv;
    __syncthreads();
    bf8 a0 = *(const bf8*)Afr;
    bf8 a1 = *(const bf8*)(Afr + 16 * LDT);
    bf8 b0 = *(const bf8*)Bfr;
    bf8 b1 = *(const bf8*)(Bfr + 16 * LDT);
    acc00 = mfma16(a0, b0, acc00);
    acc01 = mfma16(a0, b1, acc01);
    acc10 = mfma16(a1, b0, acc10);
    acc11 = mfma16(a1, b1, acc11);
    __syncthreads();
  }
#pragma unroll
  for (int mi = 0; mi < 2; ++mi) {
    f32x4 r0 = mi ? acc10 : acc00;
    f32x4 r1 = mi ? acc11 : acc01;
#pragma unroll
    for (int r = 0; r < 4; ++r) {
      int lr = wm + mi * 16 + quad * 4 + r;
      int mm = mS[lr];
      if (mm < 0) continue;
#pragma unroll
      for (int ni = 0; ni < 2; ++ni) {
        int d = wn + ni * 16 + lrow;
        feat[(size_t)mm * 512 + h * 64 + d] = ni ? r1[r] : r0[r];
      }
    }
  }
}

// ---------------- LayerNorm over W, eps=1e-5 (in-place safe) -----------------
template <int W>
__global__ __launch_bounds__(256) void ln_k(const float* __restrict__ in,
                                            float* __restrict__ out,
                                            const float* __restrict__ g,
                                            const float* __restrict__ bb) {
  constexpr int PT = W / 256;
  __shared__ float red[256];
  int row = blockIdx.x, tid = threadIdx.x;
  const float* xr = in + (size_t)row * W;
  float v[PT];
  float s = 0.f, sq = 0.f;
#pragma unroll
  for (int p = 0; p < PT; ++p) {
    v[p] = xr[tid + p * 256];
    s += v[p];
    sq += v[p] * v[p];
  }
  red[tid] = s;
  __syncthreads();
  for (int off = 128; off; off >>= 1) {
    if (tid < off) red[tid] += red[tid + off];
    __syncthreads();
  }
  float mean = red[0] * (1.0f / W);
  __syncthreads();
  red[tid] = sq;
  __syncthreads();
  for (int off = 128; off; off >>= 1) {
    if (tid < off) red[tid] += red[tid + off];
    __syncthreads();
  }
  float var = red[0] * (1.0f / W) - mean * mean;
  float is = 1.0f / sqrtf(var + 1e-5f);
#pragma unroll
  for (int p = 0; p < PT; ++p) {
    int c = tid + p * 256;
    out[(size_t)row * W + c] = (v[p] - mean) * is * g[c] + bb[c];
  }
}

// ---------------- final: out_x = LN(x + scatter(ag)/sqrt2) -------------------
__global__ __launch_bounds__(256) void outx_k(
    const float* __restrict__ x, const float* __restrict__ ag,
    const int* __restrict__ inv, const float* __restrict__ g,
    const float* __restrict__ bb, float* __restrict__ out) {
  __shared__ float red[256];
  int n = blockIdx.x, tid = threadIdx.x;
  int mi = inv[n];
  float v = x[(size_t)n * 256 + tid];
  if (mi >= 0) v += ag[(size_t)mi * 256 + tid] * RSQRT2;
  red[tid] = v;
  __syncthreads();
  for (int off = 128; off; off >>= 1) {
    if (tid < off) red[tid] += red[tid + off];
    __syncthreads();
  }
  float mean = red[0] * (1.0f / 256.0f);
  __syncthreads();
  red[tid] = v * v;
  __syncthreads();
  for (int off = 128; off; off >>= 1) {
    if (tid < off) red[tid] += red[tid + off];
    __syncthreads();
  }
  float var = red[0] * (1.0f / 256.0f) - mean * mean;
  float is = 1.0f / sqrtf(var + 1e-5f);
  out[(size_t)n * 256 + tid] = (v - mean) * is * g[tid] + bb[tid];
}

// ---------------- index compaction -------------------------------------------
__global__ void init_idx_k(int* __restrict__ list, int* __restrict__ inv,
                           int* __restrict__ cnt, int N, int B) {
  int i = blockIdx.x * 256 + threadIdx.x;
  if (i < B * N) list[i] = -1;
  if (i < N) inv[i] = -1;
  if (i < B) cnt[i] = 0;
}

__global__ void compact_k(const int* __restrict__ pm,
                          const int* __restrict__ batch, int* __restrict__ list,
                          int* __restrict__ inv, int* __restrict__ cnt, int N) {
  int m = blockIdx.x * 256 + threadIdx.x;
  if (m >= N) return;
  int p = pm[m];
  int b = batch[p];
  int slot = atomicAdd(&cnt[b], 1);
  list[(size_t)b * N + slot] = m;
  inv[p] = m;
}

// -----------------------------------------------------------------------------
extern "C" void kernel_launch(void* const* d_in, const int* in_sizes, int n_in,
                              void* d_out, int out_size, void* d_ws,
                              size_t ws_size, hipStream_t stream) {
  const float* x = (const float*)d_in[0];
  const float* emb = (const float*)d_in[1];
  const float* mask = (const float*)d_in[2];
  const int* pm = (const int*)d_in[3];
  const int* batch = (const int*)d_in[4];
  const float* Wq = (const float*)d_in[5];
  const float* Wk = (const float*)d_in[6];
  const float* Wv = (const float*)d_in[7];
  const float* ag_s = (const float*)d_in[8];
  const float* ag_b = (const float*)d_in[9];
  const float* Wag = (const float*)d_in[10];
  const float* rls = (const float*)d_in[11];
  const float* rlb = (const float*)d_in[12];
  const float* rw1 = (const float*)d_in[13];
  const float* rb1 = (const float*)d_in[14];
  const float* rw2 = (const float*)d_in[15];
  const float* rb2 = (const float*)d_in[16];
  const float* hw = (const float*)d_in[17];
  const float* hb = (const float*)d_in[18];
  const float* ens = (const float*)d_in[19];
  const float* enb = (const float*)d_in[20];

  const int N = in_sizes[0] / 256;  // 4096
  const int B = in_sizes[2] / 512;  // 4
  const size_t MB = 1024 * 1024;

  char* wsb = (char*)d_ws;
  // phase1: Kbf(0-2) Vbf(2-4) Qbf(4-8); VT(12-14)
  // phase2: featE(0-8) packed(20-52)
  // phase3: Hb(0-4) LNb(4-8) Tb(8-12) AG(14-18)
  u16* Kbf = (u16*)wsb;
  u16* Vbf = (u16*)(wsb + 2 * MB);
  u16* Qbf = (u16*)(wsb + 4 * MB);
  u16* VT = (u16*)(wsb + 12 * MB);
  float* featE = (float*)wsb;
  float* Hb = (float*)wsb;
  float* LNb = (float*)(wsb + 4 * MB);
  float* Tb = (float*)(wsb + 8 * MB);
  float* AG = (float*)(wsb + 14 * MB);
  float* STb = (float*)(wsb + 18 * MB);
  int* list = (int*)(wsb + 19 * MB);
  int* inv = list + (size_t)B * N;
  int* cnt = inv + N;
  u16* packed = (u16*)(wsb + 20 * MB);  // 8*N*512 bf16 = 32MB

  float* out_x = (float*)d_out;
  float* out_lg = out_x + (size_t)N * 256;
  float* out_sc = out_lg + (size_t)N * 20;

  init_idx_k<<<(B * N + 255) / 256, 256, 0, stream>>>(list, inv, cnt, N, B);
  compact_k<<<(N + 255) / 256, 256, 0, stream>>>(pm, batch, list, inv, cnt, N);

  // projections -> bf16
  mgemm<EPI_NONE, true><<<dim3(8, (B * 512) / 64), 256, 0, stream>>>(
      emb, Wk, Kbf, B * 512, 512, 1280, 1280, 1280, 512, nullptr, nullptr, nullptr, nullptr);
  mgemm<EPI_NONE, true><<<dim3(8, (B * 512) / 64), 256, 0, stream>>>(
      emb, Wv, Vbf, B * 512, 512, 1280, 1280, 1280, 512, nullptr, nullptr, nullptr, nullptr);
  mgemm<EPI_NONE, true><<<dim3(8, N / 64), 256, 0, stream>>>(
      x, Wq, Qbf, N, 512, 256, 256, 256, 512, nullptr, nullptr, pm, nullptr);
  vtrans<<<dim3(16, 16, B), 256, 0, stream>>>(Vbf, VT);

  // attention
  scores_mfma<<<dim3(8, N / 64, B * 8), 256, 0, stream>>>(Qbf, Kbf, list, packed, N);
  unpack_k<<<N, 256, 0, stream>>>(packed, pm, out_sc, N);
  stats_k<<<N, 256, 0, stream>>>(packed, pm, batch, mask, STb, N);
  feat_mfma<<<dim3(1, N / 64, B * 8), 256, 0, stream>>>(packed, VT, list, STb, mask, featE, N);

  // ag = LN(feat) @ Wag^T  (LN in-place)
  ln_k<512><<<N, 256, 0, stream>>>(featE, featE, ag_s, ag_b);
  mgemm<EPI_NONE, false><<<dim3(4, N / 64), 256, 0, stream>>>(
      featE, Wag, AG, N, 256, 512, 512, 512, 256, nullptr, nullptr, nullptr, nullptr);

  // residual MLP
  const float* hin = AG;
  for (int i = 0; i < 3; ++i) {
    ln_k<256><<<N, 256, 0, stream>>>(hin, LNb, rls + i * 256, rlb + i * 256);
    mgemm<EPI_BIAS_RELU, false><<<dim3(4, N / 64), 256, 0, stream>>>(
        LNb, rw1 + (size_t)i * 65536, Tb, N, 256, 256, 256, 256, 256,
        rb1 + i * 256, nullptr, nullptr, nullptr);
    mgemm<EPI_RESID, false><<<dim3(4, N / 64), 256, 0, stream>>>(
        Tb, rw2 + (size_t)i * 65536, Hb, N, 256, 256, 256, 256, 256,
        rb2 + i * 256, hin, nullptr, nullptr);
    hin = Hb;
  }
  // head (scatter rows to pm)
  mgemm<EPI_BIAS, false><<<dim3(1, N / 64), 256, 0, stream>>>(
      Hb, hw, out_lg, N, 20, 256, 256, 256, 20, hb, nullptr, nullptr, pm);
  // final LN
  outx_k<<<N, 256, 0, stream>>>(x, AG, inv, ens, enb, out_x);
}

// Round 4
// 404.549 us; speedup vs baseline: 3.0060x; 1.1742x over previous
//
#include <hip/hip_runtime.h>
#include <math.h>

// Round 4: bf16 pre-conversion of all GEMM operands, fused K+V projection,
// and a 128x64-tile bf16-input MFMA GEMM (8 MFMA / K-step) for every big GEMM.
// Scores stay packed bf16 [h][m][s]; unpack emits the strided fp32 output.

typedef short bf8 __attribute__((ext_vector_type(8)));
typedef float f32x4 __attribute__((ext_vector_type(4)));
typedef unsigned short u16;

constexpr int LDT = 40;  // LDS row stride in shorts (32 data + 8 pad)
enum { EPI_NONE = 0, EPI_BIAS_RELU = 1, EPI_BIAS = 2, EPI_RESID = 3 };
#define RSQRT2 0.70710678118654752f

__device__ __forceinline__ u16 f2bf(float f) {
  unsigned int u = __builtin_bit_cast(unsigned int, f);
  unsigned int r = u + 0x7fffu + ((u >> 16) & 1u);  // RNE
  return (u16)(r >> 16);
}
__device__ __forceinline__ float bf2f(u16 v) {
  return __builtin_bit_cast(float, (unsigned int)v << 16);
}
__device__ __forceinline__ f32x4 mfma16(bf8 a, bf8 b, f32x4 c) {
  return __builtin_amdgcn_mfma_f32_16x16x32_bf16(a, b, c, 0, 0, 0);
}

// ---------------- batched f32 -> bf16 conversion -----------------------------
struct CvtDesc { const float* src; u16* dst; int n; };
struct CvtArgs { CvtDesc d[8]; };

__global__ __launch_bounds__(256) void cvt_k(CvtArgs a) {
  CvtDesc d = a.d[blockIdx.z];
  int i = (blockIdx.x * 256 + threadIdx.x) * 8;
  if (i >= d.n) return;
  f32x4 v0 = *(const f32x4*)(d.src + i);
  f32x4 v1 = *(const f32x4*)(d.src + i + 4);
  bf8 o;
  o[0] = (short)f2bf(v0[0]); o[1] = (short)f2bf(v0[1]);
  o[2] = (short)f2bf(v0[2]); o[3] = (short)f2bf(v0[3]);
  o[4] = (short)f2bf(v1[0]); o[5] = (short)f2bf(v1[1]);
  o[6] = (short)f2bf(v1[2]); o[7] = (short)f2bf(v1[3]);
  *(bf8*)(d.dst + i) = o;
}

// ------- 128x64-tile bf16 GEMM: C[M,N] = A[M,K](bf16) @ B[N,K](bf16)^T ------
// 4 waves, each 64x32 microtile -> 8 MFMA per BK=32 step.
template <int EPI, bool BFOUT>
__global__ __launch_bounds__(256) void mgemm2(
    const u16* __restrict__ A, const u16* __restrict__ B,
    void* __restrict__ Cv, int M, int N, int K, int lda, int ldb, int ldc,
    const float* __restrict__ bias, const float* __restrict__ Hin,
    const int* __restrict__ gatherA, const int* __restrict__ scatterC) {
  __shared__ __align__(16) u16 As[128 * LDT];
  __shared__ __align__(16) u16 Bs[64 * LDT];
  const int tid = threadIdx.x;
  const int m0 = blockIdx.y * 128, n0 = blockIdx.x * 64;
  const int wave = tid >> 6, lane = tid & 63;
  const int wm = (wave & 1) * 64, wn = (wave >> 1) * 32;
  const int lrow = lane & 15, quad = lane >> 4;
  const int srow = tid >> 2, skq = tid & 3;  // A rows srow, srow+64; B row srow

  int gr0 = m0 + srow, gr1 = m0 + srow + 64;
  int ar0 = (gr0 < M) ? (gatherA ? gatherA[gr0] : gr0) : -1;
  int ar1 = (gr1 < M) ? (gatherA ? gatherA[gr1] : gr1) : -1;
  const u16* Ap0 = (ar0 >= 0) ? A + (size_t)ar0 * lda + skq * 8 : nullptr;
  const u16* Ap1 = (ar1 >= 0) ? A + (size_t)ar1 * lda + skq * 8 : nullptr;
  const u16* Bp = (n0 + srow < N) ? B + (size_t)(n0 + srow) * ldb + skq * 8 : nullptr;
  u16* AsW0 = &As[srow * LDT + skq * 8];
  u16* AsW1 = &As[(srow + 64) * LDT + skq * 8];
  u16* BsW = &Bs[srow * LDT + skq * 8];

  f32x4 acc[4][2];
#pragma unroll
  for (int i = 0; i < 4; ++i)
#pragma unroll
    for (int j = 0; j < 2; ++j) acc[i][j] = (f32x4){0.f, 0.f, 0.f, 0.f};
  const bf8 z8 = {0, 0, 0, 0, 0, 0, 0, 0};

  for (int k0 = 0; k0 < K; k0 += 32) {
    bf8 a0 = Ap0 ? *(const bf8*)(Ap0 + k0) : z8;
    bf8 a1 = Ap1 ? *(const bf8*)(Ap1 + k0) : z8;
    bf8 bv = Bp ? *(const bf8*)(Bp + k0) : z8;
    *(bf8*)AsW0 = a0;
    *(bf8*)AsW1 = a1;
    *(bf8*)BsW = bv;
    __syncthreads();
    bf8 af[4], bfr[2];
#pragma unroll
    for (int i = 0; i < 4; ++i)
      af[i] = *(const bf8*)&As[(wm + i * 16 + lrow) * LDT + quad * 8];
#pragma unroll
    for (int j = 0; j < 2; ++j)
      bfr[j] = *(const bf8*)&Bs[(wn + j * 16 + lrow) * LDT + quad * 8];
#pragma unroll
    for (int i = 0; i < 4; ++i)
#pragma unroll
      for (int j = 0; j < 2; ++j) acc[i][j] = mfma16(af[i], bfr[j], acc[i][j]);
    __syncthreads();
  }

  float* Cf = (float*)Cv;
  u16* Cb = (u16*)Cv;
#pragma unroll
  for (int i = 0; i < 4; ++i) {
#pragma unroll
    for (int r = 0; r < 4; ++r) {
      int row = m0 + wm + i * 16 + quad * 4 + r;
      if (row >= M) continue;
      if (gatherA && gatherA[row] < 0) continue;
      int orow = scatterC ? scatterC[row] : row;
#pragma unroll
      for (int j = 0; j < 2; ++j) {
        int col = n0 + wn + j * 16 + lrow;
        if (col >= N) continue;
        float v = acc[i][j][r];
        if (EPI == EPI_BIAS_RELU) v = fmaxf(v + bias[col], 0.f);
        else if (EPI == EPI_BIAS) v += bias[col];
        else if (EPI == EPI_RESID) v = (Hin[(size_t)row * ldc + col] + v + bias[col]) * RSQRT2;
        if (BFOUT) Cb[(size_t)orow * ldc + col] = f2bf(v);
        else Cf[(size_t)orow * ldc + col] = v;
      }
    }
  }
}

// ---------------- old 64x64 fp32-input GEMM (head only, N=20) ----------------
template <int EPI>
__global__ __launch_bounds__(256) void mgemm(
    const float* __restrict__ A, const float* __restrict__ B,
    float* __restrict__ Cf, int M, int N, int K, int lda, int ldb, int ldc,
    const float* __restrict__ bias, const int* __restrict__ scatterC) {
  __shared__ __align__(16) u16 As[64 * LDT];
  __shared__ __align__(16) u16 Bs[64 * LDT];
  const int tid = threadIdx.x;
  const int m0 = blockIdx.y * 64, n0 = blockIdx.x * 64;
  const int wave = tid >> 6, lane = tid & 63;
  const int wm = (wave & 1) * 32, wn = (wave >> 1) * 32;
  const int lrow = lane & 15, quad = lane >> 4;
  const int srow = tid >> 2, skq = tid & 3;
  const float* Ap = (m0 + srow < M) ? A + (size_t)(m0 + srow) * lda + skq * 8 : nullptr;
  const float* Bp = (n0 + srow < N) ? B + (size_t)(n0 + srow) * ldb + skq * 8 : nullptr;
  u16* AsW = &As[srow * LDT + skq * 8];
  u16* BsW = &Bs[srow * LDT + skq * 8];
  const u16* Afr = &As[(wm + lrow) * LDT + quad * 8];
  const u16* Bfr = &Bs[(wn + lrow) * LDT + quad * 8];
  f32x4 acc00 = {0.f, 0.f, 0.f, 0.f}, acc01 = acc00, acc10 = acc00, acc11 = acc00;
  const bf8 z8 = {0, 0, 0, 0, 0, 0, 0, 0};
  for (int k0 = 0; k0 < K; k0 += 32) {
    bf8 av = z8, bv = z8;
    if (Ap) {
      f32x4 x0 = *(const f32x4*)(Ap + k0), x1 = *(const f32x4*)(Ap + k0 + 4);
#pragma unroll
      for (int j = 0; j < 4; ++j) { av[j] = (short)f2bf(x0[j]); av[j + 4] = (short)f2bf(x1[j]); }
    }
    if (Bp) {
      f32x4 x0 = *(const f32x4*)(Bp + k0), x1 = *(const f32x4*)(Bp + k0 + 4);
#pragma unroll
      for (int j = 0; j < 4; ++j) { bv[j] = (short)f2bf(x0[j]); bv[j + 4] = (short)f2bf(x1[j]); }
    }
    *(bf8*)AsW = av;
    *(bf8*)BsW = bv;
    __syncthreads();
    bf8 a0 = *(const bf8*)Afr;
    bf8 a1 = *(const bf8*)(Afr + 16 * LDT);
    bf8 b0 = *(const bf8*)Bfr;
    bf8 b1 = *(const bf8*)(Bfr + 16 * LDT);
    acc00 = mfma16(a0, b0, acc00);
    acc01 = mfma16(a0, b1, acc01);
    acc10 = mfma16(a1, b0, acc10);
    acc11 = mfma16(a1, b1, acc11);
    __syncthreads();
  }
#pragma unroll
  for (int mi = 0; mi < 2; ++mi) {
    f32x4 r0 = mi ? acc10 : acc00;
    f32x4 r1 = mi ? acc11 : acc01;
#pragma unroll
    for (int r = 0; r < 4; ++r) {
      int row = m0 + wm + mi * 16 + quad * 4 + r;
      if (row >= M) continue;
      int orow = scatterC ? scatterC[row] : row;
#pragma unroll
      for (int ni = 0; ni < 2; ++ni) {
        int col = n0 + wn + ni * 16 + lrow;
        if (col >= N) continue;
        float v = ni ? r1[r] : r0[r];
        if (EPI == EPI_BIAS) v += bias[col];
        Cf[(size_t)orow * ldc + col] = v;
      }
    }
  }
}

// ---------------- V transpose: KV[b][s][512+hd] -> VT[b][hd][s] (bf16) -------
__global__ __launch_bounds__(256) void vtrans(const u16* __restrict__ KV,
                                              u16* __restrict__ VT) {
  __shared__ u16 t[32][33];
  int b = blockIdx.z;
  int s0 = blockIdx.x * 32, d0 = blockIdx.y * 32;
  int tx = threadIdx.x & 31, ty = threadIdx.x >> 5;
#pragma unroll
  for (int i = 0; i < 32; i += 8)
    t[ty + i][tx] = KV[(size_t)(b * 512 + s0 + ty + i) * 1024 + 512 + d0 + tx];
  __syncthreads();
#pragma unroll
  for (int i = 0; i < 32; i += 8)
    VT[(size_t)(b * 512 + d0 + ty + i) * 512 + s0 + tx] = t[tx][ty + i];
}

// ---------------- scores: per (b,h): 64m x 64s -> packed[h][m][s] bf16 -------
__global__ __launch_bounds__(256) void scores_mfma(
    const u16* __restrict__ Q, const u16* __restrict__ KV,
    const int* __restrict__ list, u16* __restrict__ packed, int N) {
  int zb = blockIdx.z;
  int b = zb >> 3, h = zb & 7;
  int mt = blockIdx.y, st = blockIdx.x;
  const int* lst = list + (size_t)b * N + mt * 64;
  if (lst[0] < 0) return;
  __shared__ __align__(16) u16 Qs[64 * LDT];
  __shared__ __align__(16) u16 Ks[64 * LDT];
  __shared__ int mS[64];
  int tid = threadIdx.x;
  if (tid < 64) mS[tid] = lst[tid];
  int wave = tid >> 6, lane = tid & 63;
  int wm = (wave & 1) * 32, wn = (wave >> 1) * 32;
  int lrow = lane & 15, quad = lane >> 4;
  int srow = tid >> 2, skq = tid & 3;
  int m = lst[srow];
  const u16* Qp = (m >= 0) ? Q + (size_t)m * 512 + h * 64 + skq * 8 : nullptr;
  const u16* Kp = KV + (size_t)(b * 512 + st * 64 + srow) * 1024 + h * 64 + skq * 8;
  u16* QsW = &Qs[srow * LDT + skq * 8];
  u16* KsW = &Ks[srow * LDT + skq * 8];
  const u16* Afr = &Qs[(wm + lrow) * LDT + quad * 8];
  const u16* Bfr = &Ks[(wn + lrow) * LDT + quad * 8];
  f32x4 acc00 = {0.f, 0.f, 0.f, 0.f}, acc01 = acc00, acc10 = acc00, acc11 = acc00;
  const bf8 z8 = {0, 0, 0, 0, 0, 0, 0, 0};
#pragma unroll
  for (int k0 = 0; k0 < 64; k0 += 32) {
    bf8 qv = Qp ? *(const bf8*)(Qp + k0) : z8;
    bf8 kv = *(const bf8*)(Kp + k0);
    *(bf8*)QsW = qv;
    *(bf8*)KsW = kv;
    __syncthreads();
    bf8 a0 = *(const bf8*)Afr;
    bf8 a1 = *(const bf8*)(Afr + 16 * LDT);
    bf8 b0 = *(const bf8*)Bfr;
    bf8 b1 = *(const bf8*)(Bfr + 16 * LDT);
    acc00 = mfma16(a0, b0, acc00);
    acc01 = mfma16(a0, b1, acc01);
    acc10 = mfma16(a1, b0, acc10);
    acc11 = mfma16(a1, b1, acc11);
    __syncthreads();
  }
#pragma unroll
  for (int mi = 0; mi < 2; ++mi) {
    f32x4 r0 = mi ? acc10 : acc00;
    f32x4 r1 = mi ? acc11 : acc01;
#pragma unroll
    for (int r = 0; r < 4; ++r) {
      int lr = wm + mi * 16 + quad * 4 + r;
      int mm = mS[lr];
      if (mm < 0) continue;
      u16* prow = packed + ((size_t)h * N + mm) * 512 + st * 64;
#pragma unroll
      for (int ni = 0; ni < 2; ++ni)
        prow[wn + ni * 16 + lrow] = f2bf((ni ? r1[r] : r0[r]) * 0.125f);
    }
  }
}

// ---------------- unpack: packed[h][m][s] -> out_sc[pm[m]][s][h] fp32 --------
__global__ __launch_bounds__(256) void unpack_k(const u16* __restrict__ packed,
                                                const int* __restrict__ pm,
                                                float* __restrict__ out_sc,
                                                int N) {
  __shared__ u16 Ls[8 * 520];
  int m = blockIdx.x, tid = threadIdx.x;
  int h = tid >> 5, c = (tid & 31) * 16;
  const u16* row = packed + ((size_t)h * N + m) * 512 + c;
  *(bf8*)&Ls[h * 520 + c] = *(const bf8*)row;
  *(bf8*)&Ls[h * 520 + c + 8] = *(const bf8*)(row + 8);
  __syncthreads();
  float* orow = out_sc + (size_t)pm[m] * 4096;
#pragma unroll
  for (int i = 0; i < 16; ++i) {
    int e = tid + i * 256;
    orow[e] = bf2f(Ls[(e & 7) * 520 + (e >> 3)]);
  }
}

// ---------------- softmax stats per (m,h) from packed ------------------------
__global__ __launch_bounds__(256) void stats_k(
    const u16* __restrict__ packed, const int* __restrict__ pm,
    const int* __restrict__ batch, const float* __restrict__ mask,
    float* __restrict__ stats, int N) {
  __shared__ float red[256];
  int m = blockIdx.x, tid = threadIdx.x;
  int h = tid >> 5, t = tid & 31;
  int b = batch[pm[m]];
  const u16* row = packed + ((size_t)h * N + m) * 512;
  float vals[16];
#pragma unroll
  for (int i = 0; i < 16; ++i) vals[i] = bf2f(row[t + i * 32]);
  float mx = -1e30f;
#pragma unroll
  for (int i = 0; i < 16; ++i) mx = fmaxf(mx, vals[i]);
  red[tid] = mx;
  __syncthreads();
  for (int off = 16; off; off >>= 1) {
    if (t < off) red[tid] = fmaxf(red[tid], red[tid + off]);
    __syncthreads();
  }
  float hmax = red[tid & ~31];
  __syncthreads();
  const float* mrow = mask + (size_t)b * 512;
  float se = 0.f, ms = 0.f;
#pragma unroll
  for (int i = 0; i < 16; ++i) {
    float e = __expf(vals[i] - hmax);
    se += e;
    ms += e * mrow[t + i * 32];
  }
  red[tid] = se;
  __syncthreads();
  for (int off = 16; off; off >>= 1) {
    if (t < off) red[tid] += red[tid + off];
    __syncthreads();
  }
  float sumexp = red[tid & ~31];
  __syncthreads();
  red[tid] = ms;
  __syncthreads();
  for (int off = 16; off; off >>= 1) {
    if (t < off) red[tid] += red[tid + off];
    __syncthreads();
  }
  float msum = red[tid & ~31];
  if (t == 0) {
    stats[(size_t)m * 16 + h * 2] = hmax;
    stats[(size_t)m * 16 + h * 2 + 1] = 1.0f / (msum + 1e-6f * sumexp);
  }
}

// ---------------- feat: per (b,h): 64m x 64d, K=S=512 -> feat bf16 -----------
__global__ __launch_bounds__(256) void feat_mfma(
    const u16* __restrict__ packed, const u16* __restrict__ VT,
    const int* __restrict__ list, const float* __restrict__ stats,
    const float* __restrict__ mask, u16* __restrict__ feat, int N) {
  int zb = blockIdx.z;
  int b = zb >> 3, h = zb & 7;
  int mt = blockIdx.y;
  const int* lst = list + (size_t)b * N + mt * 64;
  if (lst[0] < 0) return;
  __shared__ __align__(16) u16 Ws[64 * LDT];
  __shared__ __align__(16) u16 Vs[64 * LDT];
  __shared__ float mxs[64], ivs[64], mk[512];
  __shared__ int mS[64];
  int tid = threadIdx.x;
  if (tid < 64) {
    int m = lst[tid];
    mS[tid] = m;
    mxs[tid] = (m >= 0) ? stats[(size_t)m * 16 + h * 2] : 0.f;
    ivs[tid] = (m >= 0) ? stats[(size_t)m * 16 + h * 2 + 1] : 0.f;
  }
  mk[tid] = mask[(size_t)b * 512 + tid];
  mk[tid + 256] = mask[(size_t)b * 512 + 256 + tid];
  __syncthreads();
  int wave = tid >> 6, lane = tid & 63;
  int wm = (wave & 1) * 32, wn = (wave >> 1) * 32;
  int lrow = lane & 15, quad = lane >> 4;
  int srow = tid >> 2, skq = tid & 3;
  int m = mS[srow];
  float mx = mxs[srow], iv = ivs[srow];
  const u16* scp = (m >= 0) ? packed + ((size_t)h * N + m) * 512 : nullptr;
  const u16* Vp = VT + (size_t)(b * 512 + h * 64 + srow) * 512 + skq * 8;
  u16* WsW = &Ws[srow * LDT + skq * 8];
  u16* VsW = &Vs[srow * LDT + skq * 8];
  const u16* Afr = &Ws[(wm + lrow) * LDT + quad * 8];
  const u16* Bfr = &Vs[(wn + lrow) * LDT + quad * 8];
  f32x4 acc00 = {0.f, 0.f, 0.f, 0.f}, acc01 = acc00, acc10 = acc00, acc11 = acc00;
  for (int s0 = 0; s0 < 512; s0 += 32) {
    bf8 wv = {0, 0, 0, 0, 0, 0, 0, 0};
    if (scp) {
      int sb = s0 + skq * 8;
      bf8 raw = *(const bf8*)(scp + sb);
#pragma unroll
      for (int j = 0; j < 8; ++j) {
        float w = __expf(bf2f((u16)raw[j]) - mx) * mk[sb + j] * iv;
        wv[j] = (short)f2bf(w);
      }
    }
    bf8 vv = *(const bf8*)(Vp + s0);
    *(bf8*)WsW = wv;
    *(bf8*)VsW = vv;
    __syncthreads();
    bf8 a0 = *(const bf8*)Afr;
    bf8 a1 = *(const bf8*)(Afr + 16 * LDT);
    bf8 b0 = *(const bf8*)Bfr;
    bf8 b1 = *(const bf8*)(Bfr + 16 * LDT);
    acc00 = mfma16(a0, b0, acc00);
    acc01 = mfma16(a0, b1, acc01);
    acc10 = mfma16(a1, b0, acc10);
    acc11 = mfma16(a1, b1, acc11);
    __syncthreads();
  }
#pragma unroll
  for (int mi = 0; mi < 2; ++mi) {
    f32x4 r0 = mi ? acc10 : acc00;
    f32x4 r1 = mi ? acc11 : acc01;
#pragma unroll
    for (int r = 0; r < 4; ++r) {
      int lr = wm + mi * 16 + quad * 4 + r;
      int mm = mS[lr];
      if (mm < 0) continue;
#pragma unroll
      for (int ni = 0; ni < 2; ++ni) {
        int d = wn + ni * 16 + lrow;
        feat[(size_t)mm * 512 + h * 64 + d] = f2bf(ni ? r1[r] : r0[r]);
      }
    }
  }
}

// ---------------- LayerNorm over W, eps=1e-5 ---------------------------------
template <int W, bool BFIN, bool BFOUT>
__global__ __launch_bounds__(256) void ln_k(const void* __restrict__ in,
                                            void* __restrict__ out,
                                            const float* __restrict__ g,
                                            const float* __restrict__ bb) {
  constexpr int PT = W / 256;
  __shared__ float red[256];
  int row = blockIdx.x, tid = threadIdx.x;
  float v[PT];
  float s = 0.f, sq = 0.f;
#pragma unroll
  for (int p = 0; p < PT; ++p) {
    int c = tid + p * 256;
    v[p] = BFIN ? bf2f(((const u16*)in)[(size_t)row * W + c])
                : ((const float*)in)[(size_t)row * W + c];
    s += v[p];
    sq += v[p] * v[p];
  }
  red[tid] = s;
  __syncthreads();
  for (int off = 128; off; off >>= 1) {
    if (tid < off) red[tid] += red[tid + off];
    __syncthreads();
  }
  float mean = red[0] * (1.0f / W);
  __syncthreads();
  red[tid] = sq;
  __syncthreads();
  for (int off = 128; off; off >>= 1) {
    if (tid < off) red[tid] += red[tid + off];
    __syncthreads();
  }
  float var = red[0] * (1.0f / W) - mean * mean;
  float is = 1.0f / sqrtf(var + 1e-5f);
#pragma unroll
  for (int p = 0; p < PT; ++p) {
    int c = tid + p * 256;
    float o = (v[p] - mean) * is * g[c] + bb[c];
    if (BFOUT) ((u16*)out)[(size_t)row * W + c] = f2bf(o);
    else ((float*)out)[(size_t)row * W + c] = o;
  }
}

// ---------------- final: out_x = LN(x + scatter(ag)/sqrt2) -------------------
__global__ __launch_bounds__(256) void outx_k(
    const float* __restrict__ x, const float* __restrict__ ag,
    const int* __restrict__ inv, const float* __restrict__ g,
    const float* __restrict__ bb, float* __restrict__ out) {
  __shared__ float red[256];
  int n = blockIdx.x, tid = threadIdx.x;
  int mi = inv[n];
  float v = x[(size_t)n * 256 + tid];
  if (mi >= 0) v += ag[(size_t)mi * 256 + tid] * RSQRT2;
  red[tid] = v;
  __syncthreads();
  for (int off = 128; off; off >>= 1) {
    if (tid < off) red[tid] += red[tid + off];
    __syncthreads();
  }
  float mean = red[0] * (1.0f / 256.0f);
  __syncthreads();
  red[tid] = v * v;
  __syncthreads();
  for (int off = 128; off; off >>= 1) {
    if (tid < off) red[tid] += red[tid + off];
    __syncthreads();
  }
  float var = red[0] * (1.0f / 256.0f) - mean * mean;
  float is = 1.0f / sqrtf(var + 1e-5f);
  out[(size_t)n * 256 + tid] = (v - mean) * is * g[tid] + bb[tid];
}

// ---------------- index compaction -------------------------------------------
__global__ void init_idx_k(int* __restrict__ list, int* __restrict__ inv,
                           int* __restrict__ cnt, int N, int B) {
  int i = blockIdx.x * 256 + threadIdx.x;
  if (i < B * N) list[i] = -1;
  if (i < N) inv[i] = -1;
  if (i < B) cnt[i] = 0;
}

__global__ void compact_k(const int* __restrict__ pm,
                          const int* __restrict__ batch, int* __restrict__ list,
                          int* __restrict__ inv, int* __restrict__ cnt, int N) {
  int m = blockIdx.x * 256 + threadIdx.x;
  if (m >= N) return;
  int p = pm[m];
  int b = batch[p];
  int slot = atomicAdd(&cnt[b], 1);
  list[(size_t)b * N + slot] = m;
  inv[p] = m;
}

// -----------------------------------------------------------------------------
extern "C" void kernel_launch(void* const* d_in, const int* in_sizes, int n_in,
                              void* d_out, int out_size, void* d_ws,
                              size_t ws_size, hipStream_t stream) {
  const float* x = (const float*)d_in[0];
  const float* emb = (const float*)d_in[1];
  const float* mask = (const float*)d_in[2];
  const int* pm = (const int*)d_in[3];
  const int* batch = (const int*)d_in[4];
  const float* Wq = (const float*)d_in[5];
  const float* Wk = (const float*)d_in[6];
  const float* Wv = (const float*)d_in[7];
  const float* ag_s = (const float*)d_in[8];
  const float* ag_b = (const float*)d_in[9];
  const float* Wag = (const float*)d_in[10];
  const float* rls = (const float*)d_in[11];
  const float* rlb = (const float*)d_in[12];
  const float* rw1 = (const float*)d_in[13];
  const float* rb1 = (const float*)d_in[14];
  const float* rw2 = (const float*)d_in[15];
  const float* rb2 = (const float*)d_in[16];
  const float* hw = (const float*)d_in[17];
  const float* hb = (const float*)d_in[18];
  const float* ens = (const float*)d_in[19];
  const float* enb = (const float*)d_in[20];

  const int N = in_sizes[0] / 256;  // 4096
  const int B = in_sizes[2] / 512;  // 4

  char* wsb = (char*)d_ws;
  // --- ws layout (byte offsets), with temporal aliasing ---
  // conversion-phase (dead before packed is written):
  u16* embbf = (u16*)(wsb + 0);            // 2048*1280*2 = 5,242,880
  u16* xbf   = (u16*)(wsb + 5242880);      // 4096*256*2  = 2,097,152
  u16* Wkvbf = (u16*)(wsb + 7340032);      // 1024*1280*2 = 2,621,440
  u16* Wqbf  = (u16*)(wsb + 9961472);      // 512*256*2   = 262,144
  // attention phase:
  u16* packed = (u16*)(wsb + 0);           // 8*4096*512*2 = 32 MB (0..33554432)
  u16* KVbf   = (u16*)(wsb + 33554432);    // 2048*1024*2 = 4,194,304
  u16* Qbf    = (u16*)(wsb + 37748736);    // 4096*512*2  = 4,194,304
  u16* VT     = (u16*)(wsb + 41943040);    // 2048*512*2  = 2,097,152
  u16* featE  = (u16*)(wsb + 44040192);    // 4096*512*2  = 4,194,304
  // post-attention (aliases onto dead buffers):
  u16* LNF = (u16*)(wsb + 33554432);       // 4 MB, over KVbf (dead after scores)
  float* AG = (float*)(wsb + 37748736);    // 4 MB, over Qbf (dead after scores)
  u16* LNb = (u16*)(wsb + 0);              // 2 MB, over packed (dead after feat)
  u16* Tb  = (u16*)(wsb + 2097152);        // 2 MB
  float* Hb = (float*)(wsb + 4194304);     // 4 MB
  // persistent (live whole launch):
  u16* Wagbf = (u16*)(wsb + 48234496);     // 262,144
  u16* rw1bf = (u16*)(wsb + 48496640);     // 393,216
  u16* rw2bf = (u16*)(wsb + 48889856);     // 393,216
  float* STb = (float*)(wsb + 49283072);   // 262,144
  int* list  = (int*)(wsb + 49545216);     // 65,536
  int* inv   = (int*)(wsb + 49610752);     // 16,384
  int* cnt   = (int*)(wsb + 49627136);     // small   (total < 49.7 MB)

  float* out_x = (float*)d_out;
  float* out_lg = out_x + (size_t)N * 256;
  float* out_sc = out_lg + (size_t)N * 20;

  // 0. conversions + index compaction
  CvtArgs ca;
  ca.d[0] = {emb, embbf, 2 * 512 * 1280 * 2};        // B*S*SFZ = 2,621,440
  ca.d[1] = {x, xbf, 4096 * 256};
  ca.d[2] = {Wk, Wkvbf, 512 * 1280};
  ca.d[3] = {Wv, Wkvbf + 512 * 1280, 512 * 1280};
  ca.d[4] = {Wq, Wqbf, 512 * 256};
  ca.d[5] = {Wag, Wagbf, 256 * 512};
  ca.d[6] = {rw1, rw1bf, 3 * 256 * 256};
  ca.d[7] = {rw2, rw2bf, 3 * 256 * 256};
  cvt_k<<<dim3(1281, 1, 8), 256, 0, stream>>>(ca);
  init_idx_k<<<(B * N + 255) / 256, 256, 0, stream>>>(list, inv, cnt, N, B);
  compact_k<<<(N + 255) / 256, 256, 0, stream>>>(pm, batch, list, inv, cnt, N);

  // 1. fused K+V projection: (2048,1024) = embbf @ Wkvbf^T
  mgemm2<EPI_NONE, true><<<dim3(16, 16), 256, 0, stream>>>(
      embbf, Wkvbf, KVbf, B * 512, 1024, 1280, 1280, 1280, 1024,
      nullptr, nullptr, nullptr, nullptr);
  // 2. Q projection with gather
  mgemm2<EPI_NONE, true><<<dim3(8, 32), 256, 0, stream>>>(
      xbf, Wqbf, Qbf, N, 512, 256, 256, 256, 512,
      nullptr, nullptr, pm, nullptr);
  vtrans<<<dim3(16, 16, B), 256, 0, stream>>>(KVbf, VT);

  // 3. attention
  scores_mfma<<<dim3(8, N / 64, B * 8), 256, 0, stream>>>(Qbf, KVbf, list, packed, N);
  unpack_k<<<N, 256, 0, stream>>>(packed, pm, out_sc, N);
  stats_k<<<N, 256, 0, stream>>>(packed, pm, batch, mask, STb, N);
  feat_mfma<<<dim3(1, N / 64, B * 8), 256, 0, stream>>>(packed, VT, list, STb, mask, featE, N);

  // 4. ag = LN(feat) @ Wag^T
  ln_k<512, true, true><<<N, 256, 0, stream>>>(featE, LNF, ag_s, ag_b);
  mgemm2<EPI_NONE, false><<<dim3(4, 32), 256, 0, stream>>>(
      LNF, Wagbf, AG, N, 256, 512, 512, 512, 256,
      nullptr, nullptr, nullptr, nullptr);

  // 5. residual MLP
  const float* hin = AG;
  for (int i = 0; i < 3; ++i) {
    ln_k<256, false, true><<<N, 256, 0, stream>>>(hin, LNb, rls + i * 256, rlb + i * 256);
    mgemm2<EPI_BIAS_RELU, true><<<dim3(4, 32), 256, 0, stream>>>(
        LNb, rw1bf + (size_t)i * 65536, Tb, N, 256, 256, 256, 256, 256,
        rb1 + i * 256, nullptr, nullptr, nullptr);
    mgemm2<EPI_RESID, false><<<dim3(4, 32), 256, 0, stream>>>(
        Tb, rw2bf + (size_t)i * 65536, Hb, N, 256, 256, 256, 256, 256,
        rb2 + i * 256, hin, nullptr, nullptr);
    hin = Hb;
  }
  // 6. head (scatter to pm rows)
  mgemm<EPI_BIAS><<<dim3(1, 64), 256, 0, stream>>>(
      Hb, hw, out_lg, N, 20, 256, 256, 256, 20, hb, pm);
  // 7. final LN
  outx_k<<<N, 256, 0, stream>>>(x, AG, inv, ens, enb, out_x);
}

// Round 5
// 397.855 us; speedup vs baseline: 3.0565x; 1.0168x over previous
//
#include <hip/hip_runtime.h>
#include <math.h>

// Round 5: fused attention kernel (scores + softmax stats + P@V in one block,
// scores resident in LDS). Rest of the pipeline identical to round 4:
// bf16 preconvert, fused K+V projection, 128x64 MFMA GEMMs, packed scores ->
// unpack for the strided fp32 output.

typedef short bf8 __attribute__((ext_vector_type(8)));
typedef float f32x4 __attribute__((ext_vector_type(4)));
typedef unsigned short u16;

constexpr int LDT = 40;  // LDS row stride in shorts (32 data + 8 pad)
enum { EPI_NONE = 0, EPI_BIAS_RELU = 1, EPI_BIAS = 2, EPI_RESID = 3 };
#define RSQRT2 0.70710678118654752f

__device__ __forceinline__ u16 f2bf(float f) {
  unsigned int u = __builtin_bit_cast(unsigned int, f);
  unsigned int r = u + 0x7fffu + ((u >> 16) & 1u);  // RNE
  return (u16)(r >> 16);
}
__device__ __forceinline__ float bf2f(u16 v) {
  return __builtin_bit_cast(float, (unsigned int)v << 16);
}
__device__ __forceinline__ f32x4 mfma16(bf8 a, bf8 b, f32x4 c) {
  return __builtin_amdgcn_mfma_f32_16x16x32_bf16(a, b, c, 0, 0, 0);
}

// ---------------- batched f32 -> bf16 conversion -----------------------------
struct CvtDesc { const float* src; u16* dst; int n; };
struct CvtArgs { CvtDesc d[8]; };

__global__ __launch_bounds__(256) void cvt_k(CvtArgs a) {
  CvtDesc d = a.d[blockIdx.z];
  int i = (blockIdx.x * 256 + threadIdx.x) * 8;
  if (i >= d.n) return;
  f32x4 v0 = *(const f32x4*)(d.src + i);
  f32x4 v1 = *(const f32x4*)(d.src + i + 4);
  bf8 o;
  o[0] = (short)f2bf(v0[0]); o[1] = (short)f2bf(v0[1]);
  o[2] = (short)f2bf(v0[2]); o[3] = (short)f2bf(v0[3]);
  o[4] = (short)f2bf(v1[0]); o[5] = (short)f2bf(v1[1]);
  o[6] = (short)f2bf(v1[2]); o[7] = (short)f2bf(v1[3]);
  *(bf8*)(d.dst + i) = o;
}

// ------- 128x64-tile bf16 GEMM: C[M,N] = A[M,K](bf16) @ B[N,K](bf16)^T ------
template <int EPI, bool BFOUT>
__global__ __launch_bounds__(256) void mgemm2(
    const u16* __restrict__ A, const u16* __restrict__ B,
    void* __restrict__ Cv, int M, int N, int K, int lda, int ldb, int ldc,
    const float* __restrict__ bias, const float* __restrict__ Hin,
    const int* __restrict__ gatherA, const int* __restrict__ scatterC) {
  __shared__ __align__(16) u16 As[128 * LDT];
  __shared__ __align__(16) u16 Bs[64 * LDT];
  const int tid = threadIdx.x;
  const int m0 = blockIdx.y * 128, n0 = blockIdx.x * 64;
  const int wave = tid >> 6, lane = tid & 63;
  const int wm = (wave & 1) * 64, wn = (wave >> 1) * 32;
  const int lrow = lane & 15, quad = lane >> 4;
  const int srow = tid >> 2, skq = tid & 3;

  int gr0 = m0 + srow, gr1 = m0 + srow + 64;
  int ar0 = (gr0 < M) ? (gatherA ? gatherA[gr0] : gr0) : -1;
  int ar1 = (gr1 < M) ? (gatherA ? gatherA[gr1] : gr1) : -1;
  const u16* Ap0 = (ar0 >= 0) ? A + (size_t)ar0 * lda + skq * 8 : nullptr;
  const u16* Ap1 = (ar1 >= 0) ? A + (size_t)ar1 * lda + skq * 8 : nullptr;
  const u16* Bp = (n0 + srow < N) ? B + (size_t)(n0 + srow) * ldb + skq * 8 : nullptr;
  u16* AsW0 = &As[srow * LDT + skq * 8];
  u16* AsW1 = &As[(srow + 64) * LDT + skq * 8];
  u16* BsW = &Bs[srow * LDT + skq * 8];

  f32x4 acc[4][2];
#pragma unroll
  for (int i = 0; i < 4; ++i)
#pragma unroll
    for (int j = 0; j < 2; ++j) acc[i][j] = (f32x4){0.f, 0.f, 0.f, 0.f};
  const bf8 z8 = {0, 0, 0, 0, 0, 0, 0, 0};

  for (int k0 = 0; k0 < K; k0 += 32) {
    bf8 a0 = Ap0 ? *(const bf8*)(Ap0 + k0) : z8;
    bf8 a1 = Ap1 ? *(const bf8*)(Ap1 + k0) : z8;
    bf8 bv = Bp ? *(const bf8*)(Bp + k0) : z8;
    *(bf8*)AsW0 = a0;
    *(bf8*)AsW1 = a1;
    *(bf8*)BsW = bv;
    __syncthreads();
    bf8 af[4], bfr[2];
#pragma unroll
    for (int i = 0; i < 4; ++i)
      af[i] = *(const bf8*)&As[(wm + i * 16 + lrow) * LDT + quad * 8];
#pragma unroll
    for (int j = 0; j < 2; ++j)
      bfr[j] = *(const bf8*)&Bs[(wn + j * 16 + lrow) * LDT + quad * 8];
#pragma unroll
    for (int i = 0; i < 4; ++i)
#pragma unroll
      for (int j = 0; j < 2; ++j) acc[i][j] = mfma16(af[i], bfr[j], acc[i][j]);
    __syncthreads();
  }

  float* Cf = (float*)Cv;
  u16* Cb = (u16*)Cv;
#pragma unroll
  for (int i = 0; i < 4; ++i) {
#pragma unroll
    for (int r = 0; r < 4; ++r) {
      int row = m0 + wm + i * 16 + quad * 4 + r;
      if (row >= M) continue;
      if (gatherA && gatherA[row] < 0) continue;
      int orow = scatterC ? scatterC[row] : row;
#pragma unroll
      for (int j = 0; j < 2; ++j) {
        int col = n0 + wn + j * 16 + lrow;
        if (col >= N) continue;
        float v = acc[i][j][r];
        if (EPI == EPI_BIAS_RELU) v = fmaxf(v + bias[col], 0.f);
        else if (EPI == EPI_BIAS) v += bias[col];
        else if (EPI == EPI_RESID) v = (Hin[(size_t)row * ldc + col] + v + bias[col]) * RSQRT2;
        if (BFOUT) Cb[(size_t)orow * ldc + col] = f2bf(v);
        else Cf[(size_t)orow * ldc + col] = v;
      }
    }
  }
}

// ---------------- old 64x64 fp32-input GEMM (head only, N=20) ----------------
template <int EPI>
__global__ __launch_bounds__(256) void mgemm(
    const float* __restrict__ A, const float* __restrict__ B,
    float* __restrict__ Cf, int M, int N, int K, int lda, int ldb, int ldc,
    const float* __restrict__ bias, const int* __restrict__ scatterC) {
  __shared__ __align__(16) u16 As[64 * LDT];
  __shared__ __align__(16) u16 Bs[64 * LDT];
  const int tid = threadIdx.x;
  const int m0 = blockIdx.y * 64, n0 = blockIdx.x * 64;
  const int wave = tid >> 6, lane = tid & 63;
  const int wm = (wave & 1) * 32, wn = (wave >> 1) * 32;
  const int lrow = lane & 15, quad = lane >> 4;
  const int srow = tid >> 2, skq = tid & 3;
  const float* Ap = (m0 + srow < M) ? A + (size_t)(m0 + srow) * lda + skq * 8 : nullptr;
  const float* Bp = (n0 + srow < N) ? B + (size_t)(n0 + srow) * ldb + skq * 8 : nullptr;
  u16* AsW = &As[srow * LDT + skq * 8];
  u16* BsW = &Bs[srow * LDT + skq * 8];
  const u16* Afr = &As[(wm + lrow) * LDT + quad * 8];
  const u16* Bfr = &Bs[(wn + lrow) * LDT + quad * 8];
  f32x4 acc00 = {0.f, 0.f, 0.f, 0.f}, acc01 = acc00, acc10 = acc00, acc11 = acc00;
  const bf8 z8 = {0, 0, 0, 0, 0, 0, 0, 0};
  for (int k0 = 0; k0 < K; k0 += 32) {
    bf8 av = z8, bv = z8;
    if (Ap) {
      f32x4 x0 = *(const f32x4*)(Ap + k0), x1 = *(const f32x4*)(Ap + k0 + 4);
#pragma unroll
      for (int j = 0; j < 4; ++j) { av[j] = (short)f2bf(x0[j]); av[j + 4] = (short)f2bf(x1[j]); }
    }
    if (Bp) {
      f32x4 x0 = *(const f32x4*)(Bp + k0), x1 = *(const f32x4*)(Bp + k0 + 4);
#pragma unroll
      for (int j = 0; j < 4; ++j) { bv[j] = (short)f2bf(x0[j]); bv[j + 4] = (short)f2bf(x1[j]); }
    }
    *(bf8*)AsW = av;
    *(bf8*)BsW = bv;
    __syncthreads();
    bf8 a0 = *(const bf8*)Afr;
    bf8 a1 = *(const bf8*)(Afr + 16 * LDT);
    bf8 b0 = *(const bf8*)Bfr;
    bf8 b1 = *(const bf8*)(Bfr + 16 * LDT);
    acc00 = mfma16(a0, b0, acc00);
    acc01 = mfma16(a0, b1, acc01);
    acc10 = mfma16(a1, b0, acc10);
    acc11 = mfma16(a1, b1, acc11);
    __syncthreads();
  }
#pragma unroll
  for (int mi = 0; mi < 2; ++mi) {
    f32x4 r0 = mi ? acc10 : acc00;
    f32x4 r1 = mi ? acc11 : acc01;
#pragma unroll
    for (int r = 0; r < 4; ++r) {
      int row = m0 + wm + mi * 16 + quad * 4 + r;
      if (row >= M) continue;
      int orow = scatterC ? scatterC[row] : row;
#pragma unroll
      for (int ni = 0; ni < 2; ++ni) {
        int col = n0 + wn + ni * 16 + lrow;
        if (col >= N) continue;
        float v = ni ? r1[r] : r0[r];
        if (EPI == EPI_BIAS) v += bias[col];
        Cf[(size_t)orow * ldc + col] = v;
      }
    }
  }
}

// ---------------- V transpose: KV[b][s][512+hd] -> VT[b][hd][s] (bf16) -------
__global__ __launch_bounds__(256) void vtrans(const u16* __restrict__ KV,
                                              u16* __restrict__ VT) {
  __shared__ u16 t[32][33];
  int b = blockIdx.z;
  int s0 = blockIdx.x * 32, d0 = blockIdx.y * 32;
  int tx = threadIdx.x & 31, ty = threadIdx.x >> 5;
#pragma unroll
  for (int i = 0; i < 32; i += 8)
    t[ty + i][tx] = KV[(size_t)(b * 512 + s0 + ty + i) * 1024 + 512 + d0 + tx];
  __syncthreads();
#pragma unroll
  for (int i = 0; i < 32; i += 8)
    VT[(size_t)(b * 512 + d0 + ty + i) * 512 + s0 + tx] = t[tx][ty + i];
}

// ---------------- fused attention: per (b,h,mtile32) -------------------------
// Phase A: scores 32m x 512s (K=64) -> LDS W (bf16) + packed global.
// Stats: per-row max / masked-sum / eps*sum from LDS. W rebuilt as softmax wts.
// Phase B: feat 32m x 64d = W(32x512) @ VT(64x512)^T.
constexpr int WST = 520;  // W row stride (512 + 8 pad)
constexpr int QST = 72;   // Q/K row stride (64 + 8 pad)

__global__ __launch_bounds__(256) void attn_fused(
    const u16* __restrict__ Q, const u16* __restrict__ KV,
    const u16* __restrict__ VT, const int* __restrict__ list,
    const float* __restrict__ mask, u16* __restrict__ packed,
    u16* __restrict__ feat, int N) {
  const int b = blockIdx.y >> 3, h = blockIdx.y & 7;
  const int mt = blockIdx.x;
  const int* lst = list + (size_t)b * N + mt * 32;
  if (lst[0] < 0) return;

  __shared__ __align__(16) u16 Ws[32 * WST];
  __shared__ __align__(16) u16 Qs[32 * QST];
  __shared__ __align__(16) u16 KVs[64 * QST];  // K tiles (phase A) / V chunks (phase B)
  __shared__ float mk[512];
  __shared__ float red[256];
  __shared__ int mS[32];

  const int tid = threadIdx.x;
  const int wave = tid >> 6, lane = tid & 63;
  const int wm = (wave & 1) * 16, wns = (wave >> 1) * 32;
  const int lrow = lane & 15, quad = lane >> 4;
  const bf8 z8 = {0, 0, 0, 0, 0, 0, 0, 0};

  if (tid < 32) mS[tid] = lst[tid];
  mk[tid] = mask[(size_t)b * 512 + tid];
  mk[tid + 256] = mask[(size_t)b * 512 + 256 + tid];
  {  // stage Q tile: 32 rows x 64k
    int qr = tid >> 3, kq = tid & 7;
    int m = lst[qr];
    *(bf8*)&Qs[qr * QST + kq * 8] =
        (m >= 0) ? *(const bf8*)(Q + (size_t)m * 512 + h * 64 + kq * 8) : z8;
  }
  __syncthreads();

  // ---- Phase A: scores ----
  for (int st = 0; st < 8; ++st) {
#pragma unroll
    for (int i = 0; i < 2; ++i) {  // stage K tile: 64 rows x 64k
      int c = tid * 2 + i;
      int sr = c >> 3, kq = c & 7;
      *(bf8*)&KVs[sr * QST + kq * 8] =
          *(const bf8*)(KV + (size_t)(b * 512 + st * 64 + sr) * 1024 + h * 64 + kq * 8);
    }
    __syncthreads();
    f32x4 acc0 = {0.f, 0.f, 0.f, 0.f}, acc1 = acc0;
#pragma unroll
    for (int k0 = 0; k0 < 64; k0 += 32) {
      bf8 a = *(const bf8*)&Qs[(wm + lrow) * QST + k0 + quad * 8];
      bf8 b0 = *(const bf8*)&KVs[(wns + lrow) * QST + k0 + quad * 8];
      bf8 b1 = *(const bf8*)&KVs[(wns + 16 + lrow) * QST + k0 + quad * 8];
      acc0 = mfma16(a, b0, acc0);
      acc1 = mfma16(a, b1, acc1);
    }
#pragma unroll
    for (int r = 0; r < 4; ++r) {
      int lr = wm + quad * 4 + r;
      int mm = mS[lr];
      u16 v0 = f2bf(acc0[r] * 0.125f);
      u16 v1 = f2bf(acc1[r] * 0.125f);
      Ws[lr * WST + st * 64 + wns + lrow] = v0;
      Ws[lr * WST + st * 64 + wns + 16 + lrow] = v1;
      if (mm >= 0) {
        u16* prow = packed + ((size_t)h * N + mm) * 512 + st * 64;
        prow[wns + lrow] = v0;
        prow[wns + 16 + lrow] = v1;
      }
    }
    __syncthreads();
  }

  // ---- Stats + W rebuild: 8 threads per row, 64 s each ----
  {
    int row = tid >> 3, part = tid & 7;
    u16* wrow = &Ws[row * WST + part * 64];
    const float* mkp = &mk[part * 64];
    float mx = -1e30f;
#pragma unroll
    for (int j = 0; j < 64; ++j) mx = fmaxf(mx, bf2f(wrow[j]));
    red[tid] = mx;
    __syncthreads();
    if (part < 4) red[tid] = fmaxf(red[tid], red[tid + 4]);
    __syncthreads();
    if (part < 2) red[tid] = fmaxf(red[tid], red[tid + 2]);
    __syncthreads();
    if (part < 1) red[tid] = fmaxf(red[tid], red[tid + 1]);
    __syncthreads();
    mx = red[row * 8];
    __syncthreads();
    float se = 0.f, ms = 0.f;
#pragma unroll
    for (int j = 0; j < 64; ++j) {
      float e = __expf(bf2f(wrow[j]) - mx);
      se += e;
      ms += e * mkp[j];
    }
    red[tid] = se;
    __syncthreads();
    if (part < 4) red[tid] += red[tid + 4];
    __syncthreads();
    if (part < 2) red[tid] += red[tid + 2];
    __syncthreads();
    if (part < 1) red[tid] += red[tid + 1];
    __syncthreads();
    se = red[row * 8];
    __syncthreads();
    red[tid] = ms;
    __syncthreads();
    if (part < 4) red[tid] += red[tid + 4];
    __syncthreads();
    if (part < 2) red[tid] += red[tid + 2];
    __syncthreads();
    if (part < 1) red[tid] += red[tid + 1];
    __syncthreads();
    ms = red[row * 8];
    float iv = 1.0f / (ms + 1e-6f * se);
#pragma unroll
    for (int j = 0; j < 64; ++j) {
      float w = __expf(bf2f(wrow[j]) - mx) * mkp[j] * iv;
      wrow[j] = f2bf(w);
    }
  }
  __syncthreads();

  // ---- Phase B: feat = W @ VT^T  (32m x 64d, K=512) ----
  const int wnd = wns;  // reuse wave n-split for d
  f32x4 acc0 = {0.f, 0.f, 0.f, 0.f}, acc1 = acc0;
  int vr = tid >> 2, vq = tid & 3;
  const u16* Vp = VT + (size_t)(b * 512 + h * 64 + vr) * 512 + vq * 8;
  for (int s0 = 0; s0 < 512; s0 += 32) {
    *(bf8*)&KVs[vr * LDT + vq * 8] = *(const bf8*)(Vp + s0);
    __syncthreads();
    bf8 a = *(const bf8*)&Ws[(wm + lrow) * WST + s0 + quad * 8];
    bf8 b0 = *(const bf8*)&KVs[(wnd + lrow) * LDT + quad * 8];
    bf8 b1 = *(const bf8*)&KVs[(wnd + 16 + lrow) * LDT + quad * 8];
    acc0 = mfma16(a, b0, acc0);
    acc1 = mfma16(a, b1, acc1);
    __syncthreads();
  }
#pragma unroll
  for (int r = 0; r < 4; ++r) {
    int lr = wm + quad * 4 + r;
    int mm = mS[lr];
    if (mm < 0) continue;
    u16* frow = feat + (size_t)mm * 512 + h * 64;
    frow[wnd + lrow] = f2bf(acc0[r]);
    frow[wnd + 16 + lrow] = f2bf(acc1[r]);
  }
}

// ---------------- unpack: packed[h][m][s] -> out_sc[pm[m]][s][h] fp32 --------
__global__ __launch_bounds__(256) void unpack_k(const u16* __restrict__ packed,
                                                const int* __restrict__ pm,
                                                float* __restrict__ out_sc,
                                                int N) {
  __shared__ u16 Ls[8 * 520];
  int m = blockIdx.x, tid = threadIdx.x;
  int h = tid >> 5, c = (tid & 31) * 16;
  const u16* row = packed + ((size_t)h * N + m) * 512 + c;
  *(bf8*)&Ls[h * 520 + c] = *(const bf8*)row;
  *(bf8*)&Ls[h * 520 + c + 8] = *(const bf8*)(row + 8);
  __syncthreads();
  float* orow = out_sc + (size_t)pm[m] * 4096;
#pragma unroll
  for (int i = 0; i < 16; ++i) {
    int e = tid + i * 256;
    orow[e] = bf2f(Ls[(e & 7) * 520 + (e >> 3)]);
  }
}

// ---------------- LayerNorm over W, eps=1e-5 ---------------------------------
template <int W, bool BFIN, bool BFOUT>
__global__ __launch_bounds__(256) void ln_k(const void* __restrict__ in,
                                            void* __restrict__ out,
                                            const float* __restrict__ g,
                                            const float* __restrict__ bb) {
  constexpr int PT = W / 256;
  __shared__ float red[256];
  int row = blockIdx.x, tid = threadIdx.x;
  float v[PT];
  float s = 0.f, sq = 0.f;
#pragma unroll
  for (int p = 0; p < PT; ++p) {
    int c = tid + p * 256;
    v[p] = BFIN ? bf2f(((const u16*)in)[(size_t)row * W + c])
                : ((const float*)in)[(size_t)row * W + c];
    s += v[p];
    sq += v[p] * v[p];
  }
  red[tid] = s;
  __syncthreads();
  for (int off = 128; off; off >>= 1) {
    if (tid < off) red[tid] += red[tid + off];
    __syncthreads();
  }
  float mean = red[0] * (1.0f / W);
  __syncthreads();
  red[tid] = sq;
  __syncthreads();
  for (int off = 128; off; off >>= 1) {
    if (tid < off) red[tid] += red[tid + off];
    __syncthreads();
  }
  float var = red[0] * (1.0f / W) - mean * mean;
  float is = 1.0f / sqrtf(var + 1e-5f);
#pragma unroll
  for (int p = 0; p < PT; ++p) {
    int c = tid + p * 256;
    float o = (v[p] - mean) * is * g[c] + bb[c];
    if (BFOUT) ((u16*)out)[(size_t)row * W + c] = f2bf(o);
    else ((float*)out)[(size_t)row * W + c] = o;
  }
}

// ---------------- final: out_x = LN(x + scatter(ag)/sqrt2) -------------------
__global__ __launch_bounds__(256) void outx_k(
    const float* __restrict__ x, const float* __restrict__ ag,
    const int* __restrict__ inv, const float* __restrict__ g,
    const float* __restrict__ bb, float* __restrict__ out) {
  __shared__ float red[256];
  int n = blockIdx.x, tid = threadIdx.x;
  int mi = inv[n];
  float v = x[(size_t)n * 256 + tid];
  if (mi >= 0) v += ag[(size_t)mi * 256 + tid] * RSQRT2;
  red[tid] = v;
  __syncthreads();
  for (int off = 128; off; off >>= 1) {
    if (tid < off) red[tid] += red[tid + off];
    __syncthreads();
  }
  float mean = red[0] * (1.0f / 256.0f);
  __syncthreads();
  red[tid] = v * v;
  __syncthreads();
  for (int off = 128; off; off >>= 1) {
    if (tid < off) red[tid] += red[tid + off];
    __syncthreads();
  }
  float var = red[0] * (1.0f / 256.0f) - mean * mean;
  float is = 1.0f / sqrtf(var + 1e-5f);
  out[(size_t)n * 256 + tid] = (v - mean) * is * g[tid] + bb[tid];
}

// ---------------- index compaction -------------------------------------------
__global__ void init_idx_k(int* __restrict__ list, int* __restrict__ inv,
                           int* __restrict__ cnt, int N, int B) {
  int i = blockIdx.x * 256 + threadIdx.x;
  if (i < B * N) list[i] = -1;
  if (i < N) inv[i] = -1;
  if (i < B) cnt[i] = 0;
}

__global__ void compact_k(const int* __restrict__ pm,
                          const int* __restrict__ batch, int* __restrict__ list,
                          int* __restrict__ inv, int* __restrict__ cnt, int N) {
  int m = blockIdx.x * 256 + threadIdx.x;
  if (m >= N) return;
  int p = pm[m];
  int b = batch[p];
  int slot = atomicAdd(&cnt[b], 1);
  list[(size_t)b * N + slot] = m;
  inv[p] = m;
}

// -----------------------------------------------------------------------------
extern "C" void kernel_launch(void* const* d_in, const int* in_sizes, int n_in,
                              void* d_out, int out_size, void* d_ws,
                              size_t ws_size, hipStream_t stream) {
  const float* x = (const float*)d_in[0];
  const float* emb = (const float*)d_in[1];
  const float* mask = (const float*)d_in[2];
  const int* pm = (const int*)d_in[3];
  const int* batch = (const int*)d_in[4];
  const float* Wq = (const float*)d_in[5];
  const float* Wk = (const float*)d_in[6];
  const float* Wv = (const float*)d_in[7];
  const float* ag_s = (const float*)d_in[8];
  const float* ag_b = (const float*)d_in[9];
  const float* Wag = (const float*)d_in[10];
  const float* rls = (const float*)d_in[11];
  const float* rlb = (const float*)d_in[12];
  const float* rw1 = (const float*)d_in[13];
  const float* rb1 = (const float*)d_in[14];
  const float* rw2 = (const float*)d_in[15];
  const float* rb2 = (const float*)d_in[16];
  const float* hw = (const float*)d_in[17];
  const float* hb = (const float*)d_in[18];
  const float* ens = (const float*)d_in[19];
  const float* enb = (const float*)d_in[20];

  const int N = in_sizes[0] / 256;  // 4096
  const int B = in_sizes[2] / 512;  // 4

  char* wsb = (char*)d_ws;
  // conversion-phase (dead before packed is written):
  u16* embbf = (u16*)(wsb + 0);
  u16* xbf   = (u16*)(wsb + 5242880);
  u16* Wkvbf = (u16*)(wsb + 7340032);
  u16* Wqbf  = (u16*)(wsb + 9961472);
  // attention phase:
  u16* packed = (u16*)(wsb + 0);           // 32 MB
  u16* KVbf   = (u16*)(wsb + 33554432);    // 4 MB
  u16* Qbf    = (u16*)(wsb + 37748736);    // 4 MB
  u16* VT     = (u16*)(wsb + 41943040);    // 2 MB
  u16* featE  = (u16*)(wsb + 44040192);    // 4 MB
  // post-attention (aliases onto dead buffers):
  u16* LNF = (u16*)(wsb + 33554432);       // over KVbf
  float* AG = (float*)(wsb + 37748736);    // over Qbf
  u16* LNb = (u16*)(wsb + 0);              // over packed (dead after unpack)
  u16* Tb  = (u16*)(wsb + 2097152);
  float* Hb = (float*)(wsb + 4194304);
  // persistent:
  u16* Wagbf = (u16*)(wsb + 48234496);
  u16* rw1bf = (u16*)(wsb + 48496640);
  u16* rw2bf = (u16*)(wsb + 48889856);
  int* list  = (int*)(wsb + 49545216);
  int* inv   = (int*)(wsb + 49610752);
  int* cnt   = (int*)(wsb + 49627136);

  float* out_x = (float*)d_out;
  float* out_lg = out_x + (size_t)N * 256;
  float* out_sc = out_lg + (size_t)N * 20;

  // 0. conversions + index compaction
  CvtArgs ca;
  ca.d[0] = {emb, embbf, 2 * 512 * 1280 * 2};
  ca.d[1] = {x, xbf, 4096 * 256};
  ca.d[2] = {Wk, Wkvbf, 512 * 1280};
  ca.d[3] = {Wv, Wkvbf + 512 * 1280, 512 * 1280};
  ca.d[4] = {Wq, Wqbf, 512 * 256};
  ca.d[5] = {Wag, Wagbf, 256 * 512};
  ca.d[6] = {rw1, rw1bf, 3 * 256 * 256};
  ca.d[7] = {rw2, rw2bf, 3 * 256 * 256};
  cvt_k<<<dim3(1281, 1, 8), 256, 0, stream>>>(ca);
  init_idx_k<<<(B * N + 255) / 256, 256, 0, stream>>>(list, inv, cnt, N, B);
  compact_k<<<(N + 255) / 256, 256, 0, stream>>>(pm, batch, list, inv, cnt, N);

  // 1. fused K+V projection
  mgemm2<EPI_NONE, true><<<dim3(16, 16), 256, 0, stream>>>(
      embbf, Wkvbf, KVbf, B * 512, 1024, 1280, 1280, 1280, 1024,
      nullptr, nullptr, nullptr, nullptr);
  // 2. Q projection with gather
  mgemm2<EPI_NONE, true><<<dim3(8, 32), 256, 0, stream>>>(
      xbf, Wqbf, Qbf, N, 512, 256, 256, 256, 512,
      nullptr, nullptr, pm, nullptr);
  vtrans<<<dim3(16, 16, B), 256, 0, stream>>>(KVbf, VT);

  // 3. fused attention (scores+softmax+PV), then unpack for the fp32 output
  attn_fused<<<dim3(N / 32, B * 8), 256, 0, stream>>>(
      Qbf, KVbf, VT, list, mask, packed, featE, N);
  unpack_k<<<N, 256, 0, stream>>>(packed, pm, out_sc, N);

  // 4. ag = LN(feat) @ Wag^T
  ln_k<512, true, true><<<N, 256, 0, stream>>>(featE, LNF, ag_s, ag_b);
  mgemm2<EPI_NONE, false><<<dim3(4, 32), 256, 0, stream>>>(
      LNF, Wagbf, AG, N, 256, 512, 512, 512, 256,
      nullptr, nullptr, nullptr, nullptr);

  // 5. residual MLP
  const float* hin = AG;
  for (int i = 0; i < 3; ++i) {
    ln_k<256, false, true><<<N, 256, 0, stream>>>(hin, LNb, rls + i * 256, rlb + i * 256);
    mgemm2<EPI_BIAS_RELU, true><<<dim3(4, 32), 256, 0, stream>>>(
        LNb, rw1bf + (size_t)i * 65536, Tb, N, 256, 256, 256, 256, 256,
        rb1 + i * 256, nullptr, nullptr, nullptr);
    mgemm2<EPI_RESID, false><<<dim3(4, 32), 256, 0, stream>>>(
        Tb, rw2bf + (size_t)i * 65536, Hb, N, 256, 256, 256, 256, 256,
        rb2 + i * 256, hin, nullptr, nullptr);
    hin = Hb;
  }
  // 6. head (scatter to pm rows)
  mgemm<EPI_BIAS><<<dim3(1, 64), 256, 0, stream>>>(
      Hb, hw, out_lg, N, 20, 256, 256, 256, 20, hb, pm);
  // 7. final LN
  outx_k<<<N, 256, 0, stream>>>(x, AG, inv, ens, enb, out_x);
}